// Round 6
// baseline (1953.555 us; speedup 1.0000x reference)
//
#include <hip/hip_runtime.h>
#include <hip/hip_bf16.h>
#include <math.h>

#define Bq 64
#define Sq 5
#define Hq 50
#define Tq 30
#define Dq 300
#define Fq 400
#define Qq 200
#define G3 1200
#define KS 100
#define NCAND (Bq*Sq)
#define NCLK  (Bq*Hq)

typedef __attribute__((ext_vector_type(8))) short bf16x8;
typedef __attribute__((ext_vector_type(2))) _Float16 h2;
typedef __attribute__((ext_vector_type(4))) float f32x4;

__device__ __forceinline__ float sigmoidf_(float x){ return 1.f/(1.f+expf(-x)); }
__device__ __forceinline__ unsigned short f2bf(float x){
  __hip_bfloat16 b = __float2bfloat16(x);
  return *reinterpret_cast<unsigned short*>(&b);
}
__device__ __forceinline__ float bf2f(unsigned short u){
  __hip_bfloat16 b; *reinterpret_cast<unsigned short*>(&b) = u;
  return __bfloat162float(b);
}
// 4-element f16 dot with fp32 accumulate (2x v_dot2_f32_f16)
__device__ __forceinline__ float dot4_(uint2 h, uint2 w, float acc){
  union { unsigned u; h2 v; } a, b;
  a.u = h.x; b.u = w.x; acc = __builtin_amdgcn_fdot2(a.v, b.v, acc, false);
  a.u = h.y; b.u = w.y; acc = __builtin_amdgcn_fdot2(a.v, b.v, acc, false);
  return acc;
}

// ---------------- weight prep (one-time per call, tiny) ----------------
__global__ __launch_bounds__(256) void conv_prep_kernel(
    const float* __restrict__ c_cw, const float* __restrict__ u_cw,
    __hip_bfloat16* __restrict__ out)
{
  const int PER = 30*16384;
  int idx = blockIdx.x*256 + threadIdx.x;
  if (idx >= 2*PER) return;
  int enc = idx / PER, rem = idx - enc*PER;
  int chunk = rem >> 14;
  int e = rem & 16383;
  int sub = e >> 12;
  int col = (e >> 3) & 511;
  int j = e & 7;
  int w = chunk / 10, s = chunk - w*10;
  int d = s*32 + sub*8 + j;
  const float* cw = enc ? u_cw : c_cw;
  float v = (d < Dq && col < Fq) ? cw[(w*Dq + d)*Fq + col] : 0.f;
  out[idx] = __float2bfloat16(v);
}

__global__ __launch_bounds__(256) void att_prep_kernel(
    const float* __restrict__ c_aW, const float* __restrict__ u_aW,
    __hip_bfloat16* __restrict__ out)
{
  const int PER = 13*8192;
  int idx = blockIdx.x*256 + threadIdx.x;
  if (idx >= 2*PER) return;
  int enc = idx / PER, rem = idx - enc*PER;
  int chunk = rem >> 13;
  int e = rem & 8191;
  int sub = e >> 11;
  int col = (e >> 3) & 255;
  int j = e & 7;
  int k = chunk*32 + sub*8 + j;
  const float* aW = enc ? u_aW : c_aW;
  float v = (k < Fq && col < Qq) ? aW[k*Qq + col] : 0.f;
  out[idx] = __float2bfloat16(v);
}

// whh [1200,400] f32 -> f16 K-slice layout [q 4][k4 25][g 1200][4h]
__global__ __launch_bounds__(256) void whh_ks_prep_kernel(
    const float* __restrict__ whh, _Float16* __restrict__ out)
{
  const int TOT = 4*25*G3*4;   // 480000
  int idx = blockIdx.x*256 + threadIdx.x;
  if (idx >= TOT) return;
  int j  = idx & 3;
  int g  = (idx >> 2) % G3;
  int kq = (idx >> 2) / G3;     // q*25 + k4
  int q  = kq / 25, k4 = kq - q*25;
  out[idx] = (_Float16)whh[(size_t)g*Fq + q*KS + k4*4 + j];
}

// ---------------- fused encoder (unchanged from round 3) ----------------
#define XROWS 137
#define XBYTES (40*XROWS*16)
#define BBUF0 XBYTES
#define BCHUNK 32768
#define BBUF1 (BBUF0 + BCHUNK)
#define ABUF0 (52*128*16)
#define ACHUNK 16384
#define ABUF1 (ABUF0 + ACHUNK)
#define SCRATCH (BBUF1 + BCHUNK)
#define SMEM_BYTES (SCRATCH + 1088)

__global__ __launch_bounds__(512, 2) void encode_mfma_kernel(
    const float* __restrict__ cand_emb, const float* __restrict__ clk_emb,
    const __hip_bfloat16* __restrict__ convprep,
    const __hip_bfloat16* __restrict__ attprep,
    const float* __restrict__ c_cb, const float* __restrict__ c_ab, const float* __restrict__ c_aq,
    const float* __restrict__ c_lg, const float* __restrict__ c_lb,
    const float* __restrict__ u_cb, const float* __restrict__ u_ab, const float* __restrict__ u_aq,
    const float* __restrict__ u_lg, const float* __restrict__ u_lb,
    float* __restrict__ cand_rep, float* __restrict__ clicked_rep)
{
  __shared__ __align__(16) unsigned char smem[SMEM_BYTES];
  float* sscore = (float*)(smem + SCRATCH);
  float* sa_    = sscore + 128;
  float* red_   = sa_ + 128;

  const int b = blockIdx.x, tid = threadIdx.x;
  const bool cand = b < (NCAND/4);
  const int n0 = cand ? b*4 : (b - NCAND/4)*4;
  const float* x = (cand ? cand_emb : clk_emb) + (size_t)n0*Tq*Dq;
  const __hip_bfloat16* Wp = convprep + (cand ? 0 : 30*16384);
  const __hip_bfloat16* Ap = attprep  + (cand ? 0 : 13*8192);
  const float* cb = cand ? c_cb : u_cb;
  const float* ab = cand ? c_ab : u_ab;
  const float* aq = cand ? c_aq : u_aq;
  const float* lg = cand ? c_lg : u_lg;
  const float* lb = cand ? c_lb : u_lb;

  const int lane = tid & 63, wid = tid >> 6;
  const int mh = wid >> 2, nq = wid & 3;
  const int l15 = lane & 15, l4 = lane >> 4;

  if (tid < 128) sscore[tid] = 0.f;

  for (int i = tid; i < 40*XROWS; i += 512) {
    int c = i % 40, r = i / 40;
    float4 va = {0.f,0.f,0.f,0.f}, vb = {0.f,0.f,0.f,0.f};
    if (r < 128) {
      int lr = r & 31, tt = r >> 5;
      if (lr >= 1 && lr <= 30) {
        int t = lr - 1, d0 = c*8;
        if (d0 < Dq) {
          const float* src = x + (size_t)tt*Tq*Dq + t*Dq + d0;
          va = *(const float4*)src;
          if (d0 + 4 < Dq) vb = *(const float4*)(src + 4);
        }
      }
    }
    union { bf16x8 v; unsigned short u[8]; } pk;
    pk.u[0]=f2bf(va.x); pk.u[1]=f2bf(va.y); pk.u[2]=f2bf(va.z); pk.u[3]=f2bf(va.w);
    pk.u[4]=f2bf(vb.x); pk.u[5]=f2bf(vb.y); pk.u[6]=f2bf(vb.z); pk.u[7]=f2bf(vb.w);
    *(bf16x8*)(smem + (size_t)(c*XROWS + r)*16) = pk.v;
  }

  f32x4 acc[4][7];
  float cbv[7];
  #pragma unroll
  for (int nf = 0; nf < 7; ++nf) {
    int colg = (nq*7 + nf)*16 + l15;
    cbv[nf] = (colg < Fq) ? cb[colg] : 0.f;
  }
  #pragma unroll
  for (int mf = 0; mf < 4; ++mf)
    #pragma unroll
    for (int nf = 0; nf < 7; ++nf)
      acc[mf][nf] = (f32x4){cbv[nf], cbv[nf], cbv[nf], cbv[nf]};

  {
    const __hip_bfloat16* src = Wp;
    #pragma unroll
    for (int k = 0; k < 4; ++k) {
      uint4 v = *(const uint4*)(src + k*4096 + tid*8);
      *(uint4*)(smem + BBUF0 + k*8192 + tid*16) = v;
    }
  }
  __syncthreads();

  for (int step = 0; step < 30; ++step) {
    const int w = step / 10, s = step - w*10;
    const int cbuf = step & 1;
    uint4 nx0, nx1, nx2, nx3;
    const bool have = (step < 29);
    if (have) {
      const __hip_bfloat16* src = Wp + (size_t)(step+1)*16384;
      nx0 = *(const uint4*)(src + 0*4096 + tid*8);
      nx1 = *(const uint4*)(src + 1*4096 + tid*8);
      nx2 = *(const uint4*)(src + 2*4096 + tid*8);
      nx3 = *(const uint4*)(src + 3*4096 + tid*8);
    }
    bf16x8 a[4];
    #pragma unroll
    for (int mf = 0; mf < 4; ++mf) {
      int arow = mh*64 + mf*16 + l15 + w;
      int c = s*4 + l4;
      a[mf] = *(const bf16x8*)(smem + (size_t)(c*XROWS + arow)*16);
    }
    bf16x8 bb[7];
    const unsigned char* bbase = smem + (cbuf ? BBUF1 : BBUF0);
    #pragma unroll
    for (int nf = 0; nf < 7; ++nf) {
      int col = (nq*7 + nf)*16 + l15;
      bb[nf] = *(const bf16x8*)(bbase + (size_t)(l4*512 + col)*16);
    }
    #pragma unroll
    for (int mf = 0; mf < 4; ++mf)
      #pragma unroll
      for (int nf = 0; nf < 7; ++nf)
        acc[mf][nf] = __builtin_amdgcn_mfma_f32_16x16x32_bf16(a[mf], bb[nf], acc[mf][nf], 0, 0, 0);
    if (have) {
      unsigned char* obase = smem + (cbuf ? BBUF0 : BBUF1);
      *(uint4*)(obase + 0*8192 + tid*16) = nx0;
      *(uint4*)(obase + 1*8192 + tid*16) = nx1;
      *(uint4*)(obase + 2*8192 + tid*16) = nx2;
      *(uint4*)(obase + 3*8192 + tid*16) = nx3;
    }
    __syncthreads();
  }

  {
    #pragma unroll
    for (int k = 0; k < 2; ++k) {
      uint4 v = *(const uint4*)(Ap + k*4096 + tid*8);
      *(uint4*)(smem + ABUF0 + k*8192 + tid*16) = v;
    }
  }
  #pragma unroll
  for (int mf = 0; mf < 4; ++mf) {
    #pragma unroll
    for (int nf = 0; nf < 7; ++nf) {
      int colg = (nq*7 + nf)*16 + l15;
      if (colg < 416) {
        #pragma unroll
        for (int i = 0; i < 4; ++i) {
          int row = mh*64 + mf*16 + l4*4 + i;
          float v = fmaxf(acc[mf][nf][i], 0.f);
          *(unsigned short*)(smem + (size_t)((colg >> 3)*128 + row)*16 + (colg & 7)*2) = f2bf(v);
        }
      }
    }
  }
  __syncthreads();

  f32x4 acc2[4][4];
  #pragma unroll
  for (int mf = 0; mf < 4; ++mf)
    #pragma unroll
    for (int nn = 0; nn < 4; ++nn)
      acc2[mf][nn] = (f32x4){0.f,0.f,0.f,0.f};
  const int nf0  = (nq == 0) ? 0 : (1 + 3*nq);
  const int ncnt = (nq == 0) ? 4 : 3;

  for (int s2 = 0; s2 < 13; ++s2) {
    const int cbuf = s2 & 1;
    uint4 nx0, nx1;
    const bool have = (s2 < 12);
    if (have) {
      const __hip_bfloat16* src = Ap + (size_t)(s2+1)*8192;
      nx0 = *(const uint4*)(src + 0*4096 + tid*8);
      nx1 = *(const uint4*)(src + 1*4096 + tid*8);
    }
    bf16x8 a2[4];
    #pragma unroll
    for (int mf = 0; mf < 4; ++mf) {
      int row = mh*64 + mf*16 + l15;
      int fchunk = s2*4 + l4;
      a2[mf] = *(const bf16x8*)(smem + (size_t)(fchunk*128 + row)*16);
    }
    bf16x8 b2[4];
    const unsigned char* bbase = smem + (cbuf ? ABUF1 : ABUF0);
    #pragma unroll
    for (int nn = 0; nn < 4; ++nn) {
      if (nn < ncnt) {
        int col = (nf0 + nn)*16 + l15;
        b2[nn] = *(const bf16x8*)(bbase + (size_t)(l4*256 + col)*16);
      }
    }
    #pragma unroll
    for (int mf = 0; mf < 4; ++mf)
      #pragma unroll
      for (int nn = 0; nn < 4; ++nn)
        if (nn < ncnt)
          acc2[mf][nn] = __builtin_amdgcn_mfma_f32_16x16x32_bf16(a2[mf], b2[nn], acc2[mf][nn], 0, 0, 0);
    if (have) {
      unsigned char* obase = smem + (cbuf ? ABUF0 : ABUF1);
      *(uint4*)(obase + 0*8192 + tid*16) = nx0;
      *(uint4*)(obase + 1*8192 + tid*16) = nx1;
    }
    __syncthreads();
  }

  {
    float abv[4], aqv[4];
    #pragma unroll
    for (int nn = 0; nn < 4; ++nn) {
      int col = (nf0 + nn)*16 + l15;
      bool ok = (nn < ncnt) && (col < Qq);
      abv[nn] = ok ? ab[col] : 0.f;
      aqv[nn] = ok ? aq[col] : 0.f;
    }
    #pragma unroll
    for (int mf = 0; mf < 4; ++mf) {
      #pragma unroll
      for (int i = 0; i < 4; ++i) {
        float p = 0.f;
        #pragma unroll
        for (int nn = 0; nn < 4; ++nn)
          if (nn < ncnt)
            p += tanhf(acc2[mf][nn][i] + abv[nn]) * aqv[nn];
        p += __shfl_xor(p, 1); p += __shfl_xor(p, 2);
        p += __shfl_xor(p, 4); p += __shfl_xor(p, 8);
        if (l15 == 0) atomicAdd(&sscore[mh*64 + mf*16 + l4*4 + i], p);
      }
    }
  }
  __syncthreads();

  if (tid < 4) {
    float mx = -1e30f;
    for (int t = 0; t < Tq; ++t) mx = fmaxf(mx, sscore[tid*32 + t]);
    float sum = 0.f;
    for (int t = 0; t < Tq; ++t) { float e = expf(sscore[tid*32 + t] - mx); sa_[tid*32 + t] = e; sum += e; }
    float inv = 1.f / sum;
    for (int t = 0; t < Tq; ++t) sa_[tid*32 + t] *= inv;
    sa_[tid*32 + 30] = 0.f; sa_[tid*32 + 31] = 0.f;
  }
  __syncthreads();

  {
    const int tt = tid >> 7, fb = tid & 127;
    float rv[4];
    float ls = 0.f, lsq = 0.f;
    #pragma unroll
    for (int q = 0; q < 4; ++q) {
      int f = fb + q*128;
      rv[q] = 0.f;
      if (f < Fq) {
        float r = 0.f;
        const unsigned char* hb = smem + (size_t)(f >> 3)*128*16 + (f & 7)*2;
        for (int t = 0; t < Tq; ++t)
          r += sa_[tt*32 + t] * bf2f(*(const unsigned short*)(hb + (size_t)(tt*32 + t)*16));
        rv[q] = r; ls += r; lsq += r*r;
      }
    }
    #pragma unroll
    for (int off = 32; off >= 1; off >>= 1) { ls += __shfl_xor(ls, off); lsq += __shfl_xor(lsq, off); }
    if (lane == 0) { red_[wid] = ls; red_[8 + wid] = lsq; }
    __syncthreads();
    float tot  = red_[2*tt] + red_[2*tt + 1];
    float totq = red_[8 + 2*tt] + red_[8 + 2*tt + 1];
    float mu = tot * (1.f/Fq);
    float var = totq * (1.f/Fq) - mu*mu;
    float rs = rsqrtf(var + 1e-5f);
    float* dst = (cand ? cand_rep : clicked_rep) + (size_t)(n0 + tt)*Fq;
    #pragma unroll
    for (int q = 0; q < 4; ++q) {
      int f = fb + q*128;
      if (f < Fq) dst[f] = (rv[q] - mu)*rs*lg[f] + lb[f];
    }
  }
}

// ---------------- GI = clicked_rep @ wih^T + bih ----------------
__global__ __launch_bounds__(256) void gi_kernel(
    const float* __restrict__ rep, const float* __restrict__ wih, const float* __restrict__ bih,
    float* __restrict__ gi)
{
  __shared__ __align__(16) float sA[64*80];
  const int tid = threadIdx.x;
  const int rt = blockIdx.x;
  const int g  = blockIdx.y*256 + tid;
  const bool gok = g < G3;
  const float* wr = wih + (size_t)(gok ? g : 0) * Fq;
  float acc[64];
  #pragma unroll
  for (int r = 0; r < 64; ++r) acc[r] = 0.f;
  for (int kt = 0; kt < Fq; kt += 80) {
    __syncthreads();
    for (int i = tid; i < 64*80; i += 256) {
      int r = i / 80, c = i - r*80;
      sA[i] = rep[(size_t)(rt*64 + r)*Fq + kt + c];
    }
    __syncthreads();
    #pragma unroll 2
    for (int k = 0; k < 80; k += 4) {
      float w0 = wr[kt+k], w1 = wr[kt+k+1], w2 = wr[kt+k+2], w3 = wr[kt+k+3];
      #pragma unroll
      for (int r = 0; r < 64; ++r) {
        float4 a4 = *(const float4*)(sA + r*80 + k);
        acc[r] = fmaf(a4.x,w0,fmaf(a4.y,w1,fmaf(a4.z,w2,fmaf(a4.w,w3,acc[r]))));
      }
    }
  }
  if (gok) {
    float bv = bih[g];
    #pragma unroll 1
    for (int r = 0; r < 64; ++r) gi[(size_t)(rt*64+r)*G3 + g] = acc[r] + bv;
  }
}

// ---------------- GRU: K-split cooperative, 4 blocks/row ----------------
// Block (b,q) owns k/j-slice [100q,100q+100). h-slice stays local in LDS;
// only 1200-float partial-gate vectors are exchanged (double-buffered by
// step parity; per-row counter; release/acquire — round-4-proven protocol).
__global__ __launch_bounds__(256) void gru_ks_kernel(
    const float* __restrict__ gi, const _Float16* __restrict__ whhKS,
    const float* __restrict__ bhh, const int* __restrict__ lens,
    float* __restrict__ pbuf, int* __restrict__ cnt, float* __restrict__ user_rep)
{
  __shared__ __align__(8) _Float16 sh2[KS];   // f16 h-slice (matvec operand)
  __shared__ float shf[KS];                   // f32 carried h-slice
  const int bid = blockIdx.x;
  const int b = bid & 63, q = bid >> 6;       // partners bid,bid+64,... (same XCD slot)
  const int tid = threadIdx.x;
  const int len = lens[b];
  if (tid < KS) { shf[tid] = 0.f; sh2[tid] = (_Float16)0.f; }

  const int g4 = tid + 1024;
  const bool g4ok = (g4 < G3);                // tid < 176
  const uint2* wq = (const uint2*)whhKS + (size_t)q*25*G3;
  int* mycnt = cnt + b;
  const float* gb = gi + (size_t)b*Hq*G3;

  float br = 0.f, bz = 0.f, bn = 0.f;
  if (tid < KS) {
    int j = q*KS + tid;
    br = bhh[j]; bz = bhh[400 + j]; bn = bhh[800 + j];
  }
  __syncthreads();

  for (int t = 0; t < len; ++t) {
    // ---- partial matvec over own k-slice (weights L2-resident, coalesced) ----
    float a0=0.f, a1=0.f, a2=0.f, a3=0.f, a4=0.f;
    const uint2* hp = (const uint2*)sh2;
    #pragma unroll 5
    for (int k4 = 0; k4 < 25; ++k4) {
      uint2 hv = hp[k4];                       // LDS broadcast
      a0 = dot4_(hv, wq[(size_t)k4*G3 + tid      ], a0);
      a1 = dot4_(hv, wq[(size_t)k4*G3 + tid + 256], a1);
      a2 = dot4_(hv, wq[(size_t)k4*G3 + tid + 512], a2);
      a3 = dot4_(hv, wq[(size_t)k4*G3 + tid + 768], a3);
      if (g4ok) a4 = dot4_(hv, wq[(size_t)k4*G3 + g4], a4);
    }
    float* pb = pbuf + ((size_t)(t & 1)*256 + b*4 + q)*G3;
    pb[tid]       = a0;
    pb[tid + 256] = a1;
    pb[tid + 512] = a2;
    pb[tid + 768] = a3;
    if (g4ok) pb[g4] = a4;
    __threadfence();
    __syncthreads();
    if (tid == 0) {
      __hip_atomic_fetch_add(mycnt, 1, __ATOMIC_RELEASE, __HIP_MEMORY_SCOPE_AGENT);
      const int target = 4*(t + 1);
      while (__hip_atomic_load(mycnt, __ATOMIC_ACQUIRE, __HIP_MEMORY_SCOPE_AGENT) < target)
        __builtin_amdgcn_s_sleep(2);
    }
    __syncthreads();
    __threadfence();   // acquire side: invalidate L1 before reading partners' partials

    // ---- gate sum + h-update for own j-slice ----
    if (tid < KS) {
      int j = q*KS + tid;
      const float* p0 = pbuf + ((size_t)(t & 1)*256 + b*4)*G3;
      float sr = p0[j]       + p0[G3 + j]       + p0[2*G3 + j]       + p0[3*G3 + j];
      float sz = p0[400 + j] + p0[G3 + 400 + j] + p0[2*G3 + 400 + j] + p0[3*G3 + 400 + j];
      float sn = p0[800 + j] + p0[G3 + 800 + j] + p0[2*G3 + 800 + j] + p0[3*G3 + 800 + j];
      const float* gt = gb + (size_t)t*G3;
      float rg = sigmoidf_(gt[j]       + sr + br);
      float zg = sigmoidf_(gt[400 + j] + sz + bz);
      float ng = tanhf   (gt[800 + j] + rg*(sn + bn));
      float hn = (1.f - zg)*ng + zg*shf[tid];
      shf[tid] = hn;
      sh2[tid] = (_Float16)hn;
    }
    __syncthreads();
  }

  if (tid < KS) user_rep[(size_t)b*Fq + q*KS + tid] = shf[tid];
}

__global__ __launch_bounds__(64) void score_kernel(
    const float* __restrict__ cand_rep, const float* __restrict__ user_rep,
    float* __restrict__ out)
{
  const int i = blockIdx.x;
  const int b = i / Sq;
  const int lane = threadIdx.x;
  float acc = 0.f;
  for (int f = lane; f < Fq; f += 64) acc = fmaf(cand_rep[(size_t)i*Fq+f], user_rep[(size_t)b*Fq+f], acc);
  #pragma unroll
  for (int off = 32; off >= 1; off >>= 1) acc += __shfl_xor(acc, off);
  if (lane == 0) out[i] = acc;
}

extern "C" void kernel_launch(void* const* d_in, const int* in_sizes, int n_in,
                              void* d_out, int out_size, void* d_ws, size_t ws_size,
                              hipStream_t stream)
{
  const float* cand_emb = (const float*)d_in[0];
  const float* clk_emb  = (const float*)d_in[1];
  const int*   lens     = (const int*)  d_in[2];
  const float* c_cw = (const float*)d_in[3];
  const float* c_cb = (const float*)d_in[4];
  const float* c_aW = (const float*)d_in[5];
  const float* c_ab = (const float*)d_in[6];
  const float* c_aq = (const float*)d_in[7];
  const float* c_lg = (const float*)d_in[8];
  const float* c_lb = (const float*)d_in[9];
  const float* u_cw = (const float*)d_in[10];
  const float* u_cb = (const float*)d_in[11];
  const float* u_aW = (const float*)d_in[12];
  const float* u_ab = (const float*)d_in[13];
  const float* u_aq = (const float*)d_in[14];
  const float* u_lg = (const float*)d_in[15];
  const float* u_lb = (const float*)d_in[16];
  const float* wih  = (const float*)d_in[17];
  const float* whh  = (const float*)d_in[18];
  const float* bih  = (const float*)d_in[19];
  const float* bhh  = (const float*)d_in[20];

  float* ws = (float*)d_ws;
  float* cand_rep    = ws;                             // 128,000 f
  float* clicked_rep = cand_rep + NCAND*Fq;            // 1,280,000 f
  float* gi          = clicked_rep + NCLK*Fq;          // 3,840,000 f
  float* user_rep    = gi + (size_t)NCLK*G3;           // 25,600 f
  _Float16* whhKS    = (_Float16*)(user_rep + Bq*Fq);  // 480,000 halves = 240,000 f
  float* pbuf        = (float*)(whhKS + 480000);       // 2*256*1200 = 614,400 f
  int*   cnt         = (int*)(pbuf + 2*256*G3);        // 64 ints
  // bf16 encoder-prep buffers overlay gi (dead until gi_kernel runs)
  __hip_bfloat16* convprep = (__hip_bfloat16*)gi;
  __hip_bfloat16* attprep  = (__hip_bfloat16*)(gi + 491520);

  hipMemsetAsync(cnt, 0, 64*sizeof(int), stream);

  conv_prep_kernel<<<(2*30*16384 + 255)/256, 256, 0, stream>>>(c_cw, u_cw, convprep);
  att_prep_kernel<<<(2*13*8192 + 255)/256, 256, 0, stream>>>(c_aW, u_aW, attprep);
  whh_ks_prep_kernel<<<(4*25*G3*4 + 255)/256, 256, 0, stream>>>(whh, whhKS);

  encode_mfma_kernel<<<(NCAND + NCLK)/4, 512, 0, stream>>>(
      cand_emb, clk_emb, convprep, attprep,
      c_cb, c_ab, c_aq, c_lg, c_lb,
      u_cb, u_ab, u_aq, u_lg, u_lb,
      cand_rep, clicked_rep);

  gi_kernel<<<dim3(NCLK/64, 5), 256, 0, stream>>>(clicked_rep, wih, bih, gi);

  gru_ks_kernel<<<256, 256, 0, stream>>>(gi, whhKS, bhh, lens, pbuf, cnt, user_rep);

  score_kernel<<<NCAND, 64, 0, stream>>>(cand_rep, user_rep, (float*)d_out);
}

// Round 8
// 951.222 us; speedup vs baseline: 2.0537x; 2.0537x over previous
//
#include <hip/hip_runtime.h>
#include <hip/hip_bf16.h>
#include <math.h>

#define Bq 64
#define Sq 5
#define Hq 50
#define Tq 30
#define Dq 300
#define Fq 400
#define Qq 200
#define G3 1200
#define NCAND (Bq*Sq)
#define NCLK  (Bq*Hq)

typedef __attribute__((ext_vector_type(8))) short bf16x8;
typedef __attribute__((ext_vector_type(2))) _Float16 h2;
typedef __attribute__((ext_vector_type(4))) float f32x4;

__device__ __forceinline__ float sigmoidf_(float x){ return 1.f/(1.f+expf(-x)); }
__device__ __forceinline__ unsigned short f2bf(float x){
  __hip_bfloat16 b = __float2bfloat16(x);
  return *reinterpret_cast<unsigned short*>(&b);
}
__device__ __forceinline__ float bf2f(unsigned short u){
  __hip_bfloat16 b; *reinterpret_cast<unsigned short*>(&b) = u;
  return __bfloat162float(b);
}
// 8-element f16 dot with fp32 accumulate (4x v_dot2_f32_f16)
__device__ __forceinline__ float dot8_(uint4 h, uint4 w, float acc){
  union { unsigned u; h2 v; } a, b;
  a.u = h.x; b.u = w.x; acc = __builtin_amdgcn_fdot2(a.v, b.v, acc, false);
  a.u = h.y; b.u = w.y; acc = __builtin_amdgcn_fdot2(a.v, b.v, acc, false);
  a.u = h.z; b.u = w.z; acc = __builtin_amdgcn_fdot2(a.v, b.v, acc, false);
  a.u = h.w; b.u = w.w; acc = __builtin_amdgcn_fdot2(a.v, b.v, acc, false);
  return acc;
}

// ---------------- weight prep (one-time per call, tiny) ----------------
__global__ __launch_bounds__(256) void conv_prep_kernel(
    const float* __restrict__ c_cw, const float* __restrict__ u_cw,
    __hip_bfloat16* __restrict__ out)
{
  const int PER = 30*16384;
  int idx = blockIdx.x*256 + threadIdx.x;
  if (idx >= 2*PER) return;
  int enc = idx / PER, rem = idx - enc*PER;
  int chunk = rem >> 14;
  int e = rem & 16383;
  int sub = e >> 12;
  int col = (e >> 3) & 511;
  int j = e & 7;
  int w = chunk / 10, s = chunk - w*10;
  int d = s*32 + sub*8 + j;
  const float* cw = enc ? u_cw : c_cw;
  float v = (d < Dq && col < Fq) ? cw[(w*Dq + d)*Fq + col] : 0.f;
  out[idx] = __float2bfloat16(v);
}

__global__ __launch_bounds__(256) void att_prep_kernel(
    const float* __restrict__ c_aW, const float* __restrict__ u_aW,
    __hip_bfloat16* __restrict__ out)
{
  const int PER = 13*8192;
  int idx = blockIdx.x*256 + threadIdx.x;
  if (idx >= 2*PER) return;
  int enc = idx / PER, rem = idx - enc*PER;
  int chunk = rem >> 13;
  int e = rem & 8191;
  int sub = e >> 11;
  int col = (e >> 3) & 255;
  int j = e & 7;
  int k = chunk*32 + sub*8 + j;
  const float* aW = enc ? u_aW : c_aW;
  float v = (k < Fq && col < Qq) ? aW[k*Qq + col] : 0.f;
  out[idx] = __float2bfloat16(v);
}

// whh [1200,400] f32 -> f16 layout [k8 50][g 1200][8]: coalesced uint4 per (k8,g)
__global__ __launch_bounds__(256) void whh_h8_prep_kernel(
    const float* __restrict__ whh, _Float16* __restrict__ out)
{
  const int TOT = 50*G3*8;   // 480000
  int idx = blockIdx.x*256 + threadIdx.x;
  if (idx >= TOT) return;
  int j  = idx & 7;
  int g  = (idx >> 3) % G3;
  int k8 = (idx >> 3) / G3;
  out[idx] = (_Float16)whh[(size_t)g*Fq + k8*8 + j];
}

// ---------------- fused encoder (round 3 + nontemporal x loads) ----------------
#define XROWS 137
#define XBYTES (40*XROWS*16)
#define BBUF0 XBYTES
#define BCHUNK 32768
#define BBUF1 (BBUF0 + BCHUNK)
#define ABUF0 (52*128*16)
#define ACHUNK 16384
#define ABUF1 (ABUF0 + ACHUNK)
#define SCRATCH (BBUF1 + BCHUNK)
#define SMEM_BYTES (SCRATCH + 1088)

__global__ __launch_bounds__(512, 2) void encode_mfma_kernel(
    const float* __restrict__ cand_emb, const float* __restrict__ clk_emb,
    const __hip_bfloat16* __restrict__ convprep,
    const __hip_bfloat16* __restrict__ attprep,
    const float* __restrict__ c_cb, const float* __restrict__ c_ab, const float* __restrict__ c_aq,
    const float* __restrict__ c_lg, const float* __restrict__ c_lb,
    const float* __restrict__ u_cb, const float* __restrict__ u_ab, const float* __restrict__ u_aq,
    const float* __restrict__ u_lg, const float* __restrict__ u_lb,
    float* __restrict__ cand_rep, float* __restrict__ clicked_rep)
{
  __shared__ __align__(16) unsigned char smem[SMEM_BYTES];
  float* sscore = (float*)(smem + SCRATCH);
  float* sa_    = sscore + 128;
  float* red_   = sa_ + 128;

  const int b = blockIdx.x, tid = threadIdx.x;
  const bool cand = b < (NCAND/4);
  const int n0 = cand ? b*4 : (b - NCAND/4)*4;
  const float* x = (cand ? cand_emb : clk_emb) + (size_t)n0*Tq*Dq;
  const __hip_bfloat16* Wp = convprep + (cand ? 0 : 30*16384);
  const __hip_bfloat16* Ap = attprep  + (cand ? 0 : 13*8192);
  const float* cb = cand ? c_cb : u_cb;
  const float* ab = cand ? c_ab : u_ab;
  const float* aq = cand ? c_aq : u_aq;
  const float* lg = cand ? c_lg : u_lg;
  const float* lb = cand ? c_lb : u_lb;

  const int lane = tid & 63, wid = tid >> 6;
  const int mh = wid >> 2, nq = wid & 3;
  const int l15 = lane & 15, l4 = lane >> 4;

  if (tid < 128) sscore[tid] = 0.f;

  // stage x -> bf16 LDS. x is read-once: nontemporal (evict-first) so the
  // conv/att weight stream stays L2-resident (the round-7 fix).
  for (int i = tid; i < 40*XROWS; i += 512) {
    int c = i % 40, r = i / 40;
    f32x4 va = (f32x4){0.f,0.f,0.f,0.f}, vb = (f32x4){0.f,0.f,0.f,0.f};
    if (r < 128) {
      int lr = r & 31, tt = r >> 5;
      if (lr >= 1 && lr <= 30) {
        int t = lr - 1, d0 = c*8;
        if (d0 < Dq) {
          const f32x4* src = (const f32x4*)(x + (size_t)tt*Tq*Dq + t*Dq + d0);
          va = __builtin_nontemporal_load(src);
          if (d0 + 4 < Dq) vb = __builtin_nontemporal_load(src + 1);
        }
      }
    }
    union { bf16x8 v; unsigned short u[8]; } pk;
    pk.u[0]=f2bf(va.x); pk.u[1]=f2bf(va.y); pk.u[2]=f2bf(va.z); pk.u[3]=f2bf(va.w);
    pk.u[4]=f2bf(vb.x); pk.u[5]=f2bf(vb.y); pk.u[6]=f2bf(vb.z); pk.u[7]=f2bf(vb.w);
    *(bf16x8*)(smem + (size_t)(c*XROWS + r)*16) = pk.v;
  }

  f32x4 acc[4][7];
  float cbv[7];
  #pragma unroll
  for (int nf = 0; nf < 7; ++nf) {
    int colg = (nq*7 + nf)*16 + l15;
    cbv[nf] = (colg < Fq) ? cb[colg] : 0.f;
  }
  #pragma unroll
  for (int mf = 0; mf < 4; ++mf)
    #pragma unroll
    for (int nf = 0; nf < 7; ++nf)
      acc[mf][nf] = (f32x4){cbv[nf], cbv[nf], cbv[nf], cbv[nf]};

  {
    const __hip_bfloat16* src = Wp;
    #pragma unroll
    for (int k = 0; k < 4; ++k) {
      uint4 v = *(const uint4*)(src + k*4096 + tid*8);
      *(uint4*)(smem + BBUF0 + k*8192 + tid*16) = v;
    }
  }
  __syncthreads();

  for (int step = 0; step < 30; ++step) {
    const int w = step / 10, s = step - w*10;
    const int cbuf = step & 1;
    uint4 nx0, nx1, nx2, nx3;
    const bool have = (step < 29);
    if (have) {
      const __hip_bfloat16* src = Wp + (size_t)(step+1)*16384;
      nx0 = *(const uint4*)(src + 0*4096 + tid*8);
      nx1 = *(const uint4*)(src + 1*4096 + tid*8);
      nx2 = *(const uint4*)(src + 2*4096 + tid*8);
      nx3 = *(const uint4*)(src + 3*4096 + tid*8);
    }
    bf16x8 a[4];
    #pragma unroll
    for (int mf = 0; mf < 4; ++mf) {
      int arow = mh*64 + mf*16 + l15 + w;
      int c = s*4 + l4;
      a[mf] = *(const bf16x8*)(smem + (size_t)(c*XROWS + arow)*16);
    }
    bf16x8 bb[7];
    const unsigned char* bbase = smem + (cbuf ? BBUF1 : BBUF0);
    #pragma unroll
    for (int nf = 0; nf < 7; ++nf) {
      int col = (nq*7 + nf)*16 + l15;
      bb[nf] = *(const bf16x8*)(bbase + (size_t)(l4*512 + col)*16);
    }
    #pragma unroll
    for (int mf = 0; mf < 4; ++mf)
      #pragma unroll
      for (int nf = 0; nf < 7; ++nf)
        acc[mf][nf] = __builtin_amdgcn_mfma_f32_16x16x32_bf16(a[mf], bb[nf], acc[mf][nf], 0, 0, 0);
    if (have) {
      unsigned char* obase = smem + (cbuf ? BBUF0 : BBUF1);
      *(uint4*)(obase + 0*8192 + tid*16) = nx0;
      *(uint4*)(obase + 1*8192 + tid*16) = nx1;
      *(uint4*)(obase + 2*8192 + tid*16) = nx2;
      *(uint4*)(obase + 3*8192 + tid*16) = nx3;
    }
    __syncthreads();
  }

  {
    #pragma unroll
    for (int k = 0; k < 2; ++k) {
      uint4 v = *(const uint4*)(Ap + k*4096 + tid*8);
      *(uint4*)(smem + ABUF0 + k*8192 + tid*16) = v;
    }
  }
  #pragma unroll
  for (int mf = 0; mf < 4; ++mf) {
    #pragma unroll
    for (int nf = 0; nf < 7; ++nf) {
      int colg = (nq*7 + nf)*16 + l15;
      if (colg < 416) {
        #pragma unroll
        for (int i = 0; i < 4; ++i) {
          int row = mh*64 + mf*16 + l4*4 + i;
          float v = fmaxf(acc[mf][nf][i], 0.f);
          *(unsigned short*)(smem + (size_t)((colg >> 3)*128 + row)*16 + (colg & 7)*2) = f2bf(v);
        }
      }
    }
  }
  __syncthreads();

  f32x4 acc2[4][4];
  #pragma unroll
  for (int mf = 0; mf < 4; ++mf)
    #pragma unroll
    for (int nn = 0; nn < 4; ++nn)
      acc2[mf][nn] = (f32x4){0.f,0.f,0.f,0.f};
  const int nf0  = (nq == 0) ? 0 : (1 + 3*nq);
  const int ncnt = (nq == 0) ? 4 : 3;

  for (int s2 = 0; s2 < 13; ++s2) {
    const int cbuf = s2 & 1;
    uint4 nx0, nx1;
    const bool have = (s2 < 12);
    if (have) {
      const __hip_bfloat16* src = Ap + (size_t)(s2+1)*8192;
      nx0 = *(const uint4*)(src + 0*4096 + tid*8);
      nx1 = *(const uint4*)(src + 1*4096 + tid*8);
    }
    bf16x8 a2[4];
    #pragma unroll
    for (int mf = 0; mf < 4; ++mf) {
      int row = mh*64 + mf*16 + l15;
      int fchunk = s2*4 + l4;
      a2[mf] = *(const bf16x8*)(smem + (size_t)(fchunk*128 + row)*16);
    }
    bf16x8 b2[4];
    const unsigned char* bbase = smem + (cbuf ? ABUF1 : ABUF0);
    #pragma unroll
    for (int nn = 0; nn < 4; ++nn) {
      if (nn < ncnt) {
        int col = (nf0 + nn)*16 + l15;
        b2[nn] = *(const bf16x8*)(bbase + (size_t)(l4*256 + col)*16);
      }
    }
    #pragma unroll
    for (int mf = 0; mf < 4; ++mf)
      #pragma unroll
      for (int nn = 0; nn < 4; ++nn)
        if (nn < ncnt)
          acc2[mf][nn] = __builtin_amdgcn_mfma_f32_16x16x32_bf16(a2[mf], b2[nn], acc2[mf][nn], 0, 0, 0);
    if (have) {
      unsigned char* obase = smem + (cbuf ? ABUF0 : ABUF1);
      *(uint4*)(obase + 0*8192 + tid*16) = nx0;
      *(uint4*)(obase + 1*8192 + tid*16) = nx1;
    }
    __syncthreads();
  }

  {
    float abv[4], aqv[4];
    #pragma unroll
    for (int nn = 0; nn < 4; ++nn) {
      int col = (nf0 + nn)*16 + l15;
      bool ok = (nn < ncnt) && (col < Qq);
      abv[nn] = ok ? ab[col] : 0.f;
      aqv[nn] = ok ? aq[col] : 0.f;
    }
    #pragma unroll
    for (int mf = 0; mf < 4; ++mf) {
      #pragma unroll
      for (int i = 0; i < 4; ++i) {
        float p = 0.f;
        #pragma unroll
        for (int nn = 0; nn < 4; ++nn)
          if (nn < ncnt)
            p += tanhf(acc2[mf][nn][i] + abv[nn]) * aqv[nn];
        p += __shfl_xor(p, 1); p += __shfl_xor(p, 2);
        p += __shfl_xor(p, 4); p += __shfl_xor(p, 8);
        if (l15 == 0) atomicAdd(&sscore[mh*64 + mf*16 + l4*4 + i], p);
      }
    }
  }
  __syncthreads();

  if (tid < 4) {
    float mx = -1e30f;
    for (int t = 0; t < Tq; ++t) mx = fmaxf(mx, sscore[tid*32 + t]);
    float sum = 0.f;
    for (int t = 0; t < Tq; ++t) { float e = expf(sscore[tid*32 + t] - mx); sa_[tid*32 + t] = e; sum += e; }
    float inv = 1.f / sum;
    for (int t = 0; t < Tq; ++t) sa_[tid*32 + t] *= inv;
    sa_[tid*32 + 30] = 0.f; sa_[tid*32 + 31] = 0.f;
  }
  __syncthreads();

  {
    const int tt = tid >> 7, fb = tid & 127;
    float rv[4];
    float ls = 0.f, lsq = 0.f;
    #pragma unroll
    for (int q = 0; q < 4; ++q) {
      int f = fb + q*128;
      rv[q] = 0.f;
      if (f < Fq) {
        float r = 0.f;
        const unsigned char* hb = smem + (size_t)(f >> 3)*128*16 + (f & 7)*2;
        for (int t = 0; t < Tq; ++t)
          r += sa_[tt*32 + t] * bf2f(*(const unsigned short*)(hb + (size_t)(tt*32 + t)*16));
        rv[q] = r; ls += r; lsq += r*r;
      }
    }
    #pragma unroll
    for (int off = 32; off >= 1; off >>= 1) { ls += __shfl_xor(ls, off); lsq += __shfl_xor(lsq, off); }
    if (lane == 0) { red_[wid] = ls; red_[8 + wid] = lsq; }
    __syncthreads();
    float tot  = red_[2*tt] + red_[2*tt + 1];
    float totq = red_[8 + 2*tt] + red_[8 + 2*tt + 1];
    float mu = tot * (1.f/Fq);
    float var = totq * (1.f/Fq) - mu*mu;
    float rs = rsqrtf(var + 1e-5f);
    float* dst = (cand ? cand_rep : clicked_rep) + (size_t)(n0 + tt)*Fq;
    #pragma unroll
    for (int q = 0; q < 4; ++q) {
      int f = fb + q*128;
      if (f < Fq) dst[f] = (rv[q] - mu)*rs*lg[f] + lb[f];
    }
  }
}

// ---------------- GI = clicked_rep @ wih^T + bih ----------------
__global__ __launch_bounds__(256) void gi_kernel(
    const float* __restrict__ rep, const float* __restrict__ wih, const float* __restrict__ bih,
    float* __restrict__ gi)
{
  __shared__ __align__(16) float sA[64*80];
  const int tid = threadIdx.x;
  const int rt = blockIdx.x;
  const int g  = blockIdx.y*256 + tid;
  const bool gok = g < G3;
  const float* wr = wih + (size_t)(gok ? g : 0) * Fq;
  float acc[64];
  #pragma unroll
  for (int r = 0; r < 64; ++r) acc[r] = 0.f;
  for (int kt = 0; kt < Fq; kt += 80) {
    __syncthreads();
    for (int i = tid; i < 64*80; i += 256) {
      int r = i / 80, c = i - r*80;
      sA[i] = rep[(size_t)(rt*64 + r)*Fq + kt + c];
    }
    __syncthreads();
    #pragma unroll 2
    for (int k = 0; k < 80; k += 4) {
      float w0 = wr[kt+k], w1 = wr[kt+k+1], w2 = wr[kt+k+2], w3 = wr[kt+k+3];
      #pragma unroll
      for (int r = 0; r < 64; ++r) {
        float4 a4 = *(const float4*)(sA + r*80 + k);
        acc[r] = fmaf(a4.x,w0,fmaf(a4.y,w1,fmaf(a4.z,w2,fmaf(a4.w,w3,acc[r]))));
      }
    }
  }
  if (gok) {
    float bv = bih[g];
    #pragma unroll 1
    for (int r = 0; r < 64; ++r)
      __builtin_nontemporal_store(acc[r] + bv, &gi[(size_t)(rt*64+r)*G3 + g]);
  }
}

// ---------------- GRU: round-5 streaming design (proven 506 us) + nt gi loads --------
__global__ __launch_bounds__(1024) void gru_kernel(
    const float* __restrict__ gi, const _Float16* __restrict__ whhH8,
    const float* __restrict__ bhh, const int* __restrict__ lens,
    float* __restrict__ user_rep)
{
  __shared__ __align__(16) float shf[Fq];        // fp32 carried h
  __shared__ __align__(16) _Float16 sh2[Fq];     // packed f16 copy for matvec
  __shared__ float sgh[G3];
  const int b = blockIdx.x, tid = threadIdx.x;
  const int len = lens[b];
  for (int j = tid; j < Fq; j += 1024) { shf[j] = 0.f; sh2[j] = (_Float16)0.f; }
  __syncthreads();
  const int g2 = tid + 1024;
  const bool g2ok = (g2 < G3);                   // tid < 176
  const uint4* w1 = (const uint4*)whhH8 + tid;   // layout [k8][g][8h]
  const uint4* w2 = (const uint4*)whhH8 + (g2ok ? g2 : tid);
  const float bb1 = bhh[tid];
  const float bb2 = g2ok ? bhh[g2] : 0.f;
  const float* gb = gi + (size_t)b*Hq*G3;

  for (int t = 0; t < len; ++t) {
    float a1 = 0.f, a2 = 0.f;
    const uint4* hp = (const uint4*)sh2;
    #pragma unroll 5
    for (int k8 = 0; k8 < 50; ++k8) {
      uint4 hv = hp[k8];                         // LDS broadcast, 8 halves of h
      uint4 wv = w1[(size_t)k8*G3];              // coalesced 1KB/wave, L2-resident
      a1 = dot8_(hv, wv, a1);
      if (g2ok) {
        uint4 vv = w2[(size_t)k8*G3];
        a2 = dot8_(hv, vv, a2);
      }
    }
    sgh[tid] = a1 + bb1;
    if (g2ok) sgh[g2] = a2 + bb2;
    __syncthreads();
    if (tid < Fq) {
      float gr = __builtin_nontemporal_load(&gb[tid]);
      float gz = __builtin_nontemporal_load(&gb[Fq + tid]);
      float gn = __builtin_nontemporal_load(&gb[2*Fq + tid]);
      float r  = sigmoidf_(gr + sgh[tid]);
      float z  = sigmoidf_(gz + sgh[Fq + tid]);
      float nn = tanhf   (gn + r*sgh[2*Fq + tid]);
      float hn = (1.f - z)*nn + z*shf[tid];
      shf[tid] = hn;
      sh2[tid] = (_Float16)hn;
    }
    __syncthreads();
    gb += G3;
  }
  for (int j = tid; j < Fq; j += 1024) user_rep[(size_t)b*Fq + j] = shf[j];
}

__global__ __launch_bounds__(64) void score_kernel(
    const float* __restrict__ cand_rep, const float* __restrict__ user_rep,
    float* __restrict__ out)
{
  const int i = blockIdx.x;
  const int b = i / Sq;
  const int lane = threadIdx.x;
  float acc = 0.f;
  for (int f = lane; f < Fq; f += 64) acc = fmaf(cand_rep[(size_t)i*Fq+f], user_rep[(size_t)b*Fq+f], acc);
  #pragma unroll
  for (int off = 32; off >= 1; off >>= 1) acc += __shfl_xor(acc, off);
  if (lane == 0) out[i] = acc;
}

extern "C" void kernel_launch(void* const* d_in, const int* in_sizes, int n_in,
                              void* d_out, int out_size, void* d_ws, size_t ws_size,
                              hipStream_t stream)
{
  const float* cand_emb = (const float*)d_in[0];
  const float* clk_emb  = (const float*)d_in[1];
  const int*   lens     = (const int*)  d_in[2];
  const float* c_cw = (const float*)d_in[3];
  const float* c_cb = (const float*)d_in[4];
  const float* c_aW = (const float*)d_in[5];
  const float* c_ab = (const float*)d_in[6];
  const float* c_aq = (const float*)d_in[7];
  const float* c_lg = (const float*)d_in[8];
  const float* c_lb = (const float*)d_in[9];
  const float* u_cw = (const float*)d_in[10];
  const float* u_cb = (const float*)d_in[11];
  const float* u_aW = (const float*)d_in[12];
  const float* u_ab = (const float*)d_in[13];
  const float* u_aq = (const float*)d_in[14];
  const float* u_lg = (const float*)d_in[15];
  const float* u_lb = (const float*)d_in[16];
  const float* wih  = (const float*)d_in[17];
  const float* whh  = (const float*)d_in[18];
  const float* bih  = (const float*)d_in[19];
  const float* bhh  = (const float*)d_in[20];

  float* ws = (float*)d_ws;
  float* cand_rep    = ws;                        // 128,000 f
  float* clicked_rep = cand_rep + NCAND*Fq;       // +1,280,000
  float* gi          = clicked_rep + NCLK*Fq;     // +3,840,000
  float* user_rep    = gi + (size_t)NCLK*G3;      // +25,600
  _Float16* whhH8    = (_Float16*)(user_rep + Bq*Fq);  // 480,000 halves
  // bf16 encoder-prep buffers overlay gi (dead until gi_kernel runs)
  __hip_bfloat16* convprep = (__hip_bfloat16*)gi;
  __hip_bfloat16* attprep  = (__hip_bfloat16*)(gi + 491520);

  conv_prep_kernel<<<(2*30*16384 + 255)/256, 256, 0, stream>>>(c_cw, u_cw, convprep);
  att_prep_kernel<<<(2*13*8192 + 255)/256, 256, 0, stream>>>(c_aW, u_aW, attprep);
  whh_h8_prep_kernel<<<(50*G3*8 + 255)/256, 256, 0, stream>>>(whh, whhH8);

  encode_mfma_kernel<<<(NCAND + NCLK)/4, 512, 0, stream>>>(
      cand_emb, clk_emb, convprep, attprep,
      c_cb, c_ab, c_aq, c_lg, c_lb,
      u_cb, u_ab, u_aq, u_lg, u_lb,
      cand_rep, clicked_rep);

  gi_kernel<<<dim3(NCLK/64, 5), 256, 0, stream>>>(clicked_rep, wih, bih, gi);

  gru_kernel<<<Bq, 1024, 0, stream>>>(gi, whhH8, bhh, lens, user_rep);

  score_kernel<<<NCAND, 64, 0, stream>>>(cand_rep, user_rep, (float*)d_out);
}

// Round 9
// 924.885 us; speedup vs baseline: 2.1122x; 1.0285x over previous
//
#include <hip/hip_runtime.h>
#include <hip/hip_bf16.h>
#include <math.h>

#define Bq 64
#define Sq 5
#define Hq 50
#define Tq 30
#define Dq 300
#define Fq 400
#define Qq 200
#define G3 1200
#define NCAND (Bq*Sq)
#define NCLK  (Bq*Hq)

typedef __attribute__((ext_vector_type(8))) short bf16x8;
typedef __attribute__((ext_vector_type(2))) _Float16 h2;
typedef __attribute__((ext_vector_type(4))) float f32x4;

__device__ __forceinline__ float sigmoidf_(float x){ return 1.f/(1.f+expf(-x)); }
__device__ __forceinline__ unsigned short f2bf(float x){
  __hip_bfloat16 b = __float2bfloat16(x);
  return *reinterpret_cast<unsigned short*>(&b);
}
__device__ __forceinline__ float bf2f(unsigned short u){
  __hip_bfloat16 b; *reinterpret_cast<unsigned short*>(&b) = u;
  return __bfloat162float(b);
}
// async global->LDS DMA, 16B per lane. lds dest must be wave-uniform base
// (HW adds lane*16); global src is per-lane.
typedef __attribute__((address_space(1))) const unsigned g_u32;
typedef __attribute__((address_space(3))) unsigned l_u32;
__device__ __forceinline__ void glds16(const void* g, void* l){
  __builtin_amdgcn_global_load_lds((g_u32*)g, (l_u32*)l, 16, 0, 0);
}
// 8-element f16 dot with fp32 accumulate (4x v_dot2_f32_f16)
__device__ __forceinline__ float dot8_(uint4 h, uint4 w, float acc){
  union { unsigned u; h2 v; } a, b;
  a.u = h.x; b.u = w.x; acc = __builtin_amdgcn_fdot2(a.v, b.v, acc, false);
  a.u = h.y; b.u = w.y; acc = __builtin_amdgcn_fdot2(a.v, b.v, acc, false);
  a.u = h.z; b.u = w.z; acc = __builtin_amdgcn_fdot2(a.v, b.v, acc, false);
  a.u = h.w; b.u = w.w; acc = __builtin_amdgcn_fdot2(a.v, b.v, acc, false);
  return acc;
}

// ---------------- weight prep (one-time per call, tiny) ----------------
__global__ __launch_bounds__(256) void conv_prep_kernel(
    const float* __restrict__ c_cw, const float* __restrict__ u_cw,
    __hip_bfloat16* __restrict__ out)
{
  const int PER = 30*16384;
  int idx = blockIdx.x*256 + threadIdx.x;
  if (idx >= 2*PER) return;
  int enc = idx / PER, rem = idx - enc*PER;
  int chunk = rem >> 14;
  int e = rem & 16383;
  int sub = e >> 12;
  int col = (e >> 3) & 511;
  int j = e & 7;
  int w = chunk / 10, s = chunk - w*10;
  int d = s*32 + sub*8 + j;
  const float* cw = enc ? u_cw : c_cw;
  float v = (d < Dq && col < Fq) ? cw[(w*Dq + d)*Fq + col] : 0.f;
  out[idx] = __float2bfloat16(v);
}

__global__ __launch_bounds__(256) void att_prep_kernel(
    const float* __restrict__ c_aW, const float* __restrict__ u_aW,
    __hip_bfloat16* __restrict__ out)
{
  const int PER = 13*8192;
  int idx = blockIdx.x*256 + threadIdx.x;
  if (idx >= 2*PER) return;
  int enc = idx / PER, rem = idx - enc*PER;
  int chunk = rem >> 13;
  int e = rem & 8191;
  int sub = e >> 11;
  int col = (e >> 3) & 255;
  int j = e & 7;
  int k = chunk*32 + sub*8 + j;
  const float* aW = enc ? u_aW : c_aW;
  float v = (k < Fq && col < Qq) ? aW[k*Qq + col] : 0.f;
  out[idx] = __float2bfloat16(v);
}

// whh [1200,400] f32 -> f16 layout [k8 50][g 1200][8]: coalesced uint4 per (k8,g)
__global__ __launch_bounds__(256) void whh_h8_prep_kernel(
    const float* __restrict__ whh, _Float16* __restrict__ out)
{
  const int TOT = 50*G3*8;   // 480000
  int idx = blockIdx.x*256 + threadIdx.x;
  if (idx >= TOT) return;
  int j  = idx & 7;
  int g  = (idx >> 3) % G3;
  int k8 = (idx >> 3) / G3;
  out[idx] = (_Float16)whh[(size_t)g*Fq + k8*8 + j];
}

// ---------------- fused encoder (round 8 + global_load_lds weight staging) ----------
#define XROWS 137
#define XBYTES (40*XROWS*16)
#define BBUF0 XBYTES
#define BCHUNK 32768
#define BBUF1 (BBUF0 + BCHUNK)
#define ABUF0 (52*128*16)
#define ACHUNK 16384
#define ABUF1 (ABUF0 + ACHUNK)
#define SCRATCH (BBUF1 + BCHUNK)
#define SMEM_BYTES (SCRATCH + 1088)

__global__ __launch_bounds__(512, 2) void encode_mfma_kernel(
    const float* __restrict__ cand_emb, const float* __restrict__ clk_emb,
    const __hip_bfloat16* __restrict__ convprep,
    const __hip_bfloat16* __restrict__ attprep,
    const float* __restrict__ c_cb, const float* __restrict__ c_ab, const float* __restrict__ c_aq,
    const float* __restrict__ c_lg, const float* __restrict__ c_lb,
    const float* __restrict__ u_cb, const float* __restrict__ u_ab, const float* __restrict__ u_aq,
    const float* __restrict__ u_lg, const float* __restrict__ u_lb,
    float* __restrict__ cand_rep, float* __restrict__ clicked_rep)
{
  __shared__ __align__(16) unsigned char smem[SMEM_BYTES];
  float* sscore = (float*)(smem + SCRATCH);
  float* sa_    = sscore + 128;
  float* red_   = sa_ + 128;

  const int b = blockIdx.x, tid = threadIdx.x;
  const bool cand = b < (NCAND/4);
  const int n0 = cand ? b*4 : (b - NCAND/4)*4;
  const float* x = (cand ? cand_emb : clk_emb) + (size_t)n0*Tq*Dq;
  const __hip_bfloat16* Wp = convprep + (cand ? 0 : 30*16384);
  const __hip_bfloat16* Ap = attprep  + (cand ? 0 : 13*8192);
  const float* cb = cand ? c_cb : u_cb;
  const float* ab = cand ? c_ab : u_ab;
  const float* aq = cand ? c_aq : u_aq;
  const float* lg = cand ? c_lg : u_lg;
  const float* lb = cand ? c_lb : u_lb;

  const int lane = tid & 63, wid = tid >> 6;
  const int mh = wid >> 2, nq = wid & 3;
  const int l15 = lane & 15, l4 = lane >> 4;
  const int wbase16 = (tid & ~63)*16;   // wave-uniform LDS byte base for glds

  if (tid < 128) sscore[tid] = 0.f;

  // issue chunk-0 weight DMA first so it overlaps the x staging below
  #pragma unroll
  for (int k = 0; k < 4; ++k)
    glds16(Wp + k*4096 + tid*8, smem + BBUF0 + k*8192 + wbase16);

  // stage x -> bf16 LDS (read-once)
  for (int i = tid; i < 40*XROWS; i += 512) {
    int c = i % 40, r = i / 40;
    f32x4 va = (f32x4){0.f,0.f,0.f,0.f}, vb = (f32x4){0.f,0.f,0.f,0.f};
    if (r < 128) {
      int lr = r & 31, tt = r >> 5;
      if (lr >= 1 && lr <= 30) {
        int t = lr - 1, d0 = c*8;
        if (d0 < Dq) {
          const f32x4* src = (const f32x4*)(x + (size_t)tt*Tq*Dq + t*Dq + d0);
          va = __builtin_nontemporal_load(src);
          if (d0 + 4 < Dq) vb = __builtin_nontemporal_load(src + 1);
        }
      }
    }
    union { bf16x8 v; unsigned short u[8]; } pk;
    pk.u[0]=f2bf(va.x); pk.u[1]=f2bf(va.y); pk.u[2]=f2bf(va.z); pk.u[3]=f2bf(va.w);
    pk.u[4]=f2bf(vb.x); pk.u[5]=f2bf(vb.y); pk.u[6]=f2bf(vb.z); pk.u[7]=f2bf(vb.w);
    *(bf16x8*)(smem + (size_t)(c*XROWS + r)*16) = pk.v;
  }

  f32x4 acc[4][7];
  float cbv[7];
  #pragma unroll
  for (int nf = 0; nf < 7; ++nf) {
    int colg = (nq*7 + nf)*16 + l15;
    cbv[nf] = (colg < Fq) ? cb[colg] : 0.f;
  }
  #pragma unroll
  for (int mf = 0; mf < 4; ++mf)
    #pragma unroll
    for (int nf = 0; nf < 7; ++nf)
      acc[mf][nf] = (f32x4){cbv[nf], cbv[nf], cbv[nf], cbv[nf]};

  __syncthreads();   // drains chunk-0 DMA (vmcnt) + x staging

  for (int step = 0; step < 30; ++step) {
    const int w = step / 10, s = step - w*10;
    const int cbuf = step & 1;
    // issue next-chunk DMA immediately; it overlaps ds_reads + MFMAs below
    if (step < 29) {
      const __hip_bfloat16* src = Wp + (size_t)(step+1)*16384;
      unsigned char* dst = smem + (cbuf ? BBUF0 : BBUF1);
      #pragma unroll
      for (int k = 0; k < 4; ++k)
        glds16(src + k*4096 + tid*8, dst + k*8192 + wbase16);
    }
    bf16x8 a[4];
    #pragma unroll
    for (int mf = 0; mf < 4; ++mf) {
      int arow = mh*64 + mf*16 + l15 + w;
      int c = s*4 + l4;
      a[mf] = *(const bf16x8*)(smem + (size_t)(c*XROWS + arow)*16);
    }
    bf16x8 bb[7];
    const unsigned char* bbase = smem + (cbuf ? BBUF1 : BBUF0);
    #pragma unroll
    for (int nf = 0; nf < 7; ++nf) {
      int col = (nq*7 + nf)*16 + l15;
      bb[nf] = *(const bf16x8*)(bbase + (size_t)(l4*512 + col)*16);
    }
    #pragma unroll
    for (int mf = 0; mf < 4; ++mf)
      #pragma unroll
      for (int nf = 0; nf < 7; ++nf)
        acc[mf][nf] = __builtin_amdgcn_mfma_f32_16x16x32_bf16(a[mf], bb[nf], acc[mf][nf], 0, 0, 0);
    __syncthreads();   // compiler emits vmcnt(0) drain: next buffer ready
  }

  // stage att chunk 0 via DMA; overlaps the H-store below
  #pragma unroll
  for (int k = 0; k < 2; ++k)
    glds16(Ap + k*4096 + tid*8, smem + ABUF0 + k*8192 + wbase16);

  // H = relu(acc) -> bf16 LDS [fchunk][row][8]
  #pragma unroll
  for (int mf = 0; mf < 4; ++mf) {
    #pragma unroll
    for (int nf = 0; nf < 7; ++nf) {
      int colg = (nq*7 + nf)*16 + l15;
      if (colg < 416) {
        #pragma unroll
        for (int i = 0; i < 4; ++i) {
          int row = mh*64 + mf*16 + l4*4 + i;
          float v = fmaxf(acc[mf][nf][i], 0.f);
          *(unsigned short*)(smem + (size_t)((colg >> 3)*128 + row)*16 + (colg & 7)*2) = f2bf(v);
        }
      }
    }
  }
  __syncthreads();

  f32x4 acc2[4][4];
  #pragma unroll
  for (int mf = 0; mf < 4; ++mf)
    #pragma unroll
    for (int nn = 0; nn < 4; ++nn)
      acc2[mf][nn] = (f32x4){0.f,0.f,0.f,0.f};
  const int nf0  = (nq == 0) ? 0 : (1 + 3*nq);
  const int ncnt = (nq == 0) ? 4 : 3;

  for (int s2 = 0; s2 < 13; ++s2) {
    const int cbuf = s2 & 1;
    if (s2 < 12) {
      const __hip_bfloat16* src = Ap + (size_t)(s2+1)*8192;
      unsigned char* dst = smem + (cbuf ? ABUF0 : ABUF1);
      #pragma unroll
      for (int k = 0; k < 2; ++k)
        glds16(src + k*4096 + tid*8, dst + k*8192 + wbase16);
    }
    bf16x8 a2[4];
    #pragma unroll
    for (int mf = 0; mf < 4; ++mf) {
      int row = mh*64 + mf*16 + l15;
      int fchunk = s2*4 + l4;
      a2[mf] = *(const bf16x8*)(smem + (size_t)(fchunk*128 + row)*16);
    }
    bf16x8 b2[4];
    const unsigned char* bbase = smem + (cbuf ? ABUF1 : ABUF0);
    #pragma unroll
    for (int nn = 0; nn < 4; ++nn) {
      if (nn < ncnt) {
        int col = (nf0 + nn)*16 + l15;
        b2[nn] = *(const bf16x8*)(bbase + (size_t)(l4*256 + col)*16);
      }
    }
    #pragma unroll
    for (int mf = 0; mf < 4; ++mf)
      #pragma unroll
      for (int nn = 0; nn < 4; ++nn)
        if (nn < ncnt)
          acc2[mf][nn] = __builtin_amdgcn_mfma_f32_16x16x32_bf16(a2[mf], b2[nn], acc2[mf][nn], 0, 0, 0);
    __syncthreads();
  }

  {
    float abv[4], aqv[4];
    #pragma unroll
    for (int nn = 0; nn < 4; ++nn) {
      int col = (nf0 + nn)*16 + l15;
      bool ok = (nn < ncnt) && (col < Qq);
      abv[nn] = ok ? ab[col] : 0.f;
      aqv[nn] = ok ? aq[col] : 0.f;
    }
    #pragma unroll
    for (int mf = 0; mf < 4; ++mf) {
      #pragma unroll
      for (int i = 0; i < 4; ++i) {
        float p = 0.f;
        #pragma unroll
        for (int nn = 0; nn < 4; ++nn)
          if (nn < ncnt)
            p += tanhf(acc2[mf][nn][i] + abv[nn]) * aqv[nn];
        p += __shfl_xor(p, 1); p += __shfl_xor(p, 2);
        p += __shfl_xor(p, 4); p += __shfl_xor(p, 8);
        if (l15 == 0) atomicAdd(&sscore[mh*64 + mf*16 + l4*4 + i], p);
      }
    }
  }
  __syncthreads();

  if (tid < 4) {
    float mx = -1e30f;
    for (int t = 0; t < Tq; ++t) mx = fmaxf(mx, sscore[tid*32 + t]);
    float sum = 0.f;
    for (int t = 0; t < Tq; ++t) { float e = expf(sscore[tid*32 + t] - mx); sa_[tid*32 + t] = e; sum += e; }
    float inv = 1.f / sum;
    for (int t = 0; t < Tq; ++t) sa_[tid*32 + t] *= inv;
    sa_[tid*32 + 30] = 0.f; sa_[tid*32 + 31] = 0.f;
  }
  __syncthreads();

  {
    const int tt = tid >> 7, fb = tid & 127;
    float rv[4];
    float ls = 0.f, lsq = 0.f;
    #pragma unroll
    for (int q = 0; q < 4; ++q) {
      int f = fb + q*128;
      rv[q] = 0.f;
      if (f < Fq) {
        float r = 0.f;
        const unsigned char* hb = smem + (size_t)(f >> 3)*128*16 + (f & 7)*2;
        for (int t = 0; t < Tq; ++t)
          r += sa_[tt*32 + t] * bf2f(*(const unsigned short*)(hb + (size_t)(tt*32 + t)*16));
        rv[q] = r; ls += r; lsq += r*r;
      }
    }
    #pragma unroll
    for (int off = 32; off >= 1; off >>= 1) { ls += __shfl_xor(ls, off); lsq += __shfl_xor(lsq, off); }
    if (lane == 0) { red_[wid] = ls; red_[8 + wid] = lsq; }
    __syncthreads();
    float tot  = red_[2*tt] + red_[2*tt + 1];
    float totq = red_[8 + 2*tt] + red_[8 + 2*tt + 1];
    float mu = tot * (1.f/Fq);
    float var = totq * (1.f/Fq) - mu*mu;
    float rs = rsqrtf(var + 1e-5f);
    float* dst = (cand ? cand_rep : clicked_rep) + (size_t)(n0 + tt)*Fq;
    #pragma unroll
    for (int q = 0; q < 4; ++q) {
      int f = fb + q*128;
      if (f < Fq) dst[f] = (rv[q] - mu)*rs*lg[f] + lb[f];
    }
  }
}

// ---------------- GI = clicked_rep @ wih^T + bih ----------------
__global__ __launch_bounds__(256) void gi_kernel(
    const float* __restrict__ rep, const float* __restrict__ wih, const float* __restrict__ bih,
    float* __restrict__ gi)
{
  __shared__ __align__(16) float sA[64*80];
  const int tid = threadIdx.x;
  const int rt = blockIdx.x;
  const int g  = blockIdx.y*256 + tid;
  const bool gok = g < G3;
  const float* wr = wih + (size_t)(gok ? g : 0) * Fq;
  float acc[64];
  #pragma unroll
  for (int r = 0; r < 64; ++r) acc[r] = 0.f;
  for (int kt = 0; kt < Fq; kt += 80) {
    __syncthreads();
    for (int i = tid; i < 64*80; i += 256) {
      int r = i / 80, c = i - r*80;
      sA[i] = rep[(size_t)(rt*64 + r)*Fq + kt + c];
    }
    __syncthreads();
    #pragma unroll 2
    for (int k = 0; k < 80; k += 4) {
      float w0 = wr[kt+k], w1 = wr[kt+k+1], w2 = wr[kt+k+2], w3 = wr[kt+k+3];
      #pragma unroll
      for (int r = 0; r < 64; ++r) {
        float4 a4 = *(const float4*)(sA + r*80 + k);
        acc[r] = fmaf(a4.x,w0,fmaf(a4.y,w1,fmaf(a4.z,w2,fmaf(a4.w,w3,acc[r]))));
      }
    }
  }
  if (gok) {
    float bv = bih[g];
    #pragma unroll 1
    for (int r = 0; r < 64; ++r)
      __builtin_nontemporal_store(acc[r] + bv, &gi[(size_t)(rt*64+r)*G3 + g]);
  }
}

// ---------------- GRU: round-5 streaming design (proven 506 us) ----------------
__global__ __launch_bounds__(1024) void gru_kernel(
    const float* __restrict__ gi, const _Float16* __restrict__ whhH8,
    const float* __restrict__ bhh, const int* __restrict__ lens,
    float* __restrict__ user_rep)
{
  __shared__ __align__(16) float shf[Fq];        // fp32 carried h
  __shared__ __align__(16) _Float16 sh2[Fq];     // packed f16 copy for matvec
  __shared__ float sgh[G3];
  const int b = blockIdx.x, tid = threadIdx.x;
  const int len = lens[b];
  for (int j = tid; j < Fq; j += 1024) { shf[j] = 0.f; sh2[j] = (_Float16)0.f; }
  __syncthreads();
  const int g2 = tid + 1024;
  const bool g2ok = (g2 < G3);                   // tid < 176
  const uint4* w1 = (const uint4*)whhH8 + tid;   // layout [k8][g][8h]
  const uint4* w2 = (const uint4*)whhH8 + (g2ok ? g2 : tid);
  const float bb1 = bhh[tid];
  const float bb2 = g2ok ? bhh[g2] : 0.f;
  const float* gb = gi + (size_t)b*Hq*G3;

  for (int t = 0; t < len; ++t) {
    float a1 = 0.f, a2 = 0.f;
    const uint4* hp = (const uint4*)sh2;
    #pragma unroll 5
    for (int k8 = 0; k8 < 50; ++k8) {
      uint4 hv = hp[k8];                         // LDS broadcast, 8 halves of h
      uint4 wv = w1[(size_t)k8*G3];              // coalesced 1KB/wave, L2-resident
      a1 = dot8_(hv, wv, a1);
      if (g2ok) {
        uint4 vv = w2[(size_t)k8*G3];
        a2 = dot8_(hv, vv, a2);
      }
    }
    sgh[tid] = a1 + bb1;
    if (g2ok) sgh[g2] = a2 + bb2;
    __syncthreads();
    if (tid < Fq) {
      float gr = __builtin_nontemporal_load(&gb[tid]);
      float gz = __builtin_nontemporal_load(&gb[Fq + tid]);
      float gn = __builtin_nontemporal_load(&gb[2*Fq + tid]);
      float r  = sigmoidf_(gr + sgh[tid]);
      float z  = sigmoidf_(gz + sgh[Fq + tid]);
      float nn = tanhf   (gn + r*sgh[2*Fq + tid]);
      float hn = (1.f - z)*nn + z*shf[tid];
      shf[tid] = hn;
      sh2[tid] = (_Float16)hn;
    }
    __syncthreads();
    gb += G3;
  }
  for (int j = tid; j < Fq; j += 1024) user_rep[(size_t)b*Fq + j] = shf[j];
}

__global__ __launch_bounds__(64) void score_kernel(
    const float* __restrict__ cand_rep, const float* __restrict__ user_rep,
    float* __restrict__ out)
{
  const int i = blockIdx.x;
  const int b = i / Sq;
  const int lane = threadIdx.x;
  float acc = 0.f;
  for (int f = lane; f < Fq; f += 64) acc = fmaf(cand_rep[(size_t)i*Fq+f], user_rep[(size_t)b*Fq+f], acc);
  #pragma unroll
  for (int off = 32; off >= 1; off >>= 1) acc += __shfl_xor(acc, off);
  if (lane == 0) out[i] = acc;
}

extern "C" void kernel_launch(void* const* d_in, const int* in_sizes, int n_in,
                              void* d_out, int out_size, void* d_ws, size_t ws_size,
                              hipStream_t stream)
{
  const float* cand_emb = (const float*)d_in[0];
  const float* clk_emb  = (const float*)d_in[1];
  const int*   lens     = (const int*)  d_in[2];
  const float* c_cw = (const float*)d_in[3];
  const float* c_cb = (const float*)d_in[4];
  const float* c_aW = (const float*)d_in[5];
  const float* c_ab = (const float*)d_in[6];
  const float* c_aq = (const float*)d_in[7];
  const float* c_lg = (const float*)d_in[8];
  const float* c_lb = (const float*)d_in[9];
  const float* u_cw = (const float*)d_in[10];
  const float* u_cb = (const float*)d_in[11];
  const float* u_aW = (const float*)d_in[12];
  const float* u_ab = (const float*)d_in[13];
  const float* u_aq = (const float*)d_in[14];
  const float* u_lg = (const float*)d_in[15];
  const float* u_lb = (const float*)d_in[16];
  const float* wih  = (const float*)d_in[17];
  const float* whh  = (const float*)d_in[18];
  const float* bih  = (const float*)d_in[19];
  const float* bhh  = (const float*)d_in[20];

  float* ws = (float*)d_ws;
  float* cand_rep    = ws;                        // 128,000 f
  float* clicked_rep = cand_rep + NCAND*Fq;       // +1,280,000
  float* gi          = clicked_rep + NCLK*Fq;     // +3,840,000
  float* user_rep    = gi + (size_t)NCLK*G3;      // +25,600
  _Float16* whhH8    = (_Float16*)(user_rep + Bq*Fq);  // 480,000 halves
  // bf16 encoder-prep buffers overlay gi (dead until gi_kernel runs)
  __hip_bfloat16* convprep = (__hip_bfloat16*)gi;
  __hip_bfloat16* attprep  = (__hip_bfloat16*)(gi + 491520);

  conv_prep_kernel<<<(2*30*16384 + 255)/256, 256, 0, stream>>>(c_cw, u_cw, convprep);
  att_prep_kernel<<<(2*13*8192 + 255)/256, 256, 0, stream>>>(c_aW, u_aW, attprep);
  whh_h8_prep_kernel<<<(50*G3*8 + 255)/256, 256, 0, stream>>>(whh, whhH8);

  encode_mfma_kernel<<<(NCAND + NCLK)/4, 512, 0, stream>>>(
      cand_emb, clk_emb, convprep, attprep,
      c_cb, c_ab, c_aq, c_lg, c_lb,
      u_cb, u_ab, u_aq, u_lg, u_lb,
      cand_rep, clicked_rep);

  gi_kernel<<<dim3(NCLK/64, 5), 256, 0, stream>>>(clicked_rep, wih, bih, gi);

  gru_kernel<<<Bq, 1024, 0, stream>>>(gi, whhH8, bhh, lens, user_rep);

  score_kernel<<<NCAND, 64, 0, stream>>>(cand_rep, user_rep, (float*)d_out);
}

// Round 10
// 699.608 us; speedup vs baseline: 2.7924x; 1.3220x over previous
//
#include <hip/hip_runtime.h>
#include <hip/hip_bf16.h>
#include <math.h>

#define Bq 64
#define Sq 5
#define Hq 50
#define Tq 30
#define Dq 300
#define Fq 400
#define Qq 200
#define G3 1200
#define NCAND (Bq*Sq)
#define NCLK  (Bq*Hq)

typedef __attribute__((ext_vector_type(8))) short bf16x8;
typedef __attribute__((ext_vector_type(4))) float f32x4;

__device__ __forceinline__ float sigmoidf_(float x){ return 1.f/(1.f+expf(-x)); }
__device__ __forceinline__ unsigned short f2bf(float x){
  __hip_bfloat16 b = __float2bfloat16(x);
  return *reinterpret_cast<unsigned short*>(&b);
}
__device__ __forceinline__ float bf2f(unsigned short u){
  __hip_bfloat16 b; *reinterpret_cast<unsigned short*>(&b) = u;
  return __bfloat162float(b);
}
// async global->LDS DMA, 16B per lane (wave-uniform LDS base, HW adds lane*16)
typedef __attribute__((address_space(1))) const unsigned g_u32;
typedef __attribute__((address_space(3))) unsigned l_u32;
__device__ __forceinline__ void glds16(const void* g, void* l){
  __builtin_amdgcn_global_load_lds((g_u32*)g, (l_u32*)l, 16, 0, 0);
}
// int8x4 dot with i32 accumulate
__device__ __forceinline__ int dot4i8(unsigned a, unsigned b, int c){
#if defined(__has_builtin) && __has_builtin(__builtin_amdgcn_sdot4)
  return __builtin_amdgcn_sdot4((int)a, (int)b, c, false);
#else
  int r = c;
  r += (int)(signed char)(a)      * (int)(signed char)(b);
  r += (int)(signed char)(a>>8)   * (int)(signed char)(b>>8);
  r += (int)(signed char)(a>>16)  * (int)(signed char)(b>>16);
  r += (int)(signed char)(a>>24)  * (int)(signed char)(b>>24);
  return r;
#endif
}

// ---------------- weight prep (one-time per call, tiny) ----------------
__global__ __launch_bounds__(256) void conv_prep_kernel(
    const float* __restrict__ c_cw, const float* __restrict__ u_cw,
    __hip_bfloat16* __restrict__ out)
{
  const int PER = 30*16384;
  int idx = blockIdx.x*256 + threadIdx.x;
  if (idx >= 2*PER) return;
  int enc = idx / PER, rem = idx - enc*PER;
  int chunk = rem >> 14;
  int e = rem & 16383;
  int sub = e >> 12;
  int col = (e >> 3) & 511;
  int j = e & 7;
  int w = chunk / 10, s = chunk - w*10;
  int d = s*32 + sub*8 + j;
  const float* cw = enc ? u_cw : c_cw;
  float v = (d < Dq && col < Fq) ? cw[(w*Dq + d)*Fq + col] : 0.f;
  out[idx] = __float2bfloat16(v);
}

__global__ __launch_bounds__(256) void att_prep_kernel(
    const float* __restrict__ c_aW, const float* __restrict__ u_aW,
    __hip_bfloat16* __restrict__ out)
{
  const int PER = 13*8192;
  int idx = blockIdx.x*256 + threadIdx.x;
  if (idx >= 2*PER) return;
  int enc = idx / PER, rem = idx - enc*PER;
  int chunk = rem >> 13;
  int e = rem & 8191;
  int sub = e >> 11;
  int col = (e >> 3) & 255;
  int j = e & 7;
  int k = chunk*32 + sub*8 + j;
  const float* aW = enc ? u_aW : c_aW;
  float v = (k < Fq && col < Qq) ? aW[k*Qq + col] : 0.f;
  out[idx] = __float2bfloat16(v);
}

// whh [1200,400] f32 -> int8 with per-row scale. Layout [k16 25][g 1200][16]:
// a wave of consecutive g reads uint4 -> 1KB contiguous, coalesced.
// w ~= w8 * (mx/127); h ~= h8/127  =>  gh = acc_i32 * mx/16129.
__global__ __launch_bounds__(64) void whh_i8_prep_kernel(
    const float* __restrict__ whh, signed char* __restrict__ w8, float* __restrict__ wsc)
{
  const int g = blockIdx.x;       // 0..1199
  const int lane = threadIdx.x;   // 0..63
  const float* row = whh + (size_t)g*Fq;
  float mx = 0.f;
  for (int k = lane; k < Fq; k += 64) mx = fmaxf(mx, fabsf(row[k]));
  #pragma unroll
  for (int off = 32; off >= 1; off >>= 1) mx = fmaxf(mx, __shfl_xor(mx, off));
  float inv = (mx > 0.f) ? 127.f/mx : 0.f;
  if (lane == 0) wsc[g] = mx * (1.f/16129.f);
  for (int k = lane; k < Fq; k += 64) {
    int q = (int)rintf(row[k]*inv);
    q = max(-127, min(127, q));
    w8[((size_t)(k >> 4)*G3 + g)*16 + (k & 15)] = (signed char)q;
  }
}

// ---------------- fused encoder (round 9: MFMA + global_load_lds staging) ----------
#define XROWS 137
#define XBYTES (40*XROWS*16)
#define BBUF0 XBYTES
#define BCHUNK 32768
#define BBUF1 (BBUF0 + BCHUNK)
#define ABUF0 (52*128*16)
#define ACHUNK 16384
#define ABUF1 (ABUF0 + ACHUNK)
#define SCRATCH (BBUF1 + BCHUNK)
#define SMEM_BYTES (SCRATCH + 1088)

__global__ __launch_bounds__(512, 2) void encode_mfma_kernel(
    const float* __restrict__ cand_emb, const float* __restrict__ clk_emb,
    const __hip_bfloat16* __restrict__ convprep,
    const __hip_bfloat16* __restrict__ attprep,
    const float* __restrict__ c_cb, const float* __restrict__ c_ab, const float* __restrict__ c_aq,
    const float* __restrict__ c_lg, const float* __restrict__ c_lb,
    const float* __restrict__ u_cb, const float* __restrict__ u_ab, const float* __restrict__ u_aq,
    const float* __restrict__ u_lg, const float* __restrict__ u_lb,
    float* __restrict__ cand_rep, float* __restrict__ clicked_rep)
{
  __shared__ __align__(16) unsigned char smem[SMEM_BYTES];
  float* sscore = (float*)(smem + SCRATCH);
  float* sa_    = sscore + 128;
  float* red_   = sa_ + 128;

  const int b = blockIdx.x, tid = threadIdx.x;
  const bool cand = b < (NCAND/4);
  const int n0 = cand ? b*4 : (b - NCAND/4)*4;
  const float* x = (cand ? cand_emb : clk_emb) + (size_t)n0*Tq*Dq;
  const __hip_bfloat16* Wp = convprep + (cand ? 0 : 30*16384);
  const __hip_bfloat16* Ap = attprep  + (cand ? 0 : 13*8192);
  const float* cb = cand ? c_cb : u_cb;
  const float* ab = cand ? c_ab : u_ab;
  const float* aq = cand ? c_aq : u_aq;
  const float* lg = cand ? c_lg : u_lg;
  const float* lb = cand ? c_lb : u_lb;

  const int lane = tid & 63, wid = tid >> 6;
  const int mh = wid >> 2, nq = wid & 3;
  const int l15 = lane & 15, l4 = lane >> 4;
  const int wbase16 = (tid & ~63)*16;

  if (tid < 128) sscore[tid] = 0.f;

  #pragma unroll
  for (int k = 0; k < 4; ++k)
    glds16(Wp + k*4096 + tid*8, smem + BBUF0 + k*8192 + wbase16);

  for (int i = tid; i < 40*XROWS; i += 512) {
    int c = i % 40, r = i / 40;
    f32x4 va = (f32x4){0.f,0.f,0.f,0.f}, vb = (f32x4){0.f,0.f,0.f,0.f};
    if (r < 128) {
      int lr = r & 31, tt = r >> 5;
      if (lr >= 1 && lr <= 30) {
        int t = lr - 1, d0 = c*8;
        if (d0 < Dq) {
          const f32x4* src = (const f32x4*)(x + (size_t)tt*Tq*Dq + t*Dq + d0);
          va = __builtin_nontemporal_load(src);
          if (d0 + 4 < Dq) vb = __builtin_nontemporal_load(src + 1);
        }
      }
    }
    union { bf16x8 v; unsigned short u[8]; } pk;
    pk.u[0]=f2bf(va.x); pk.u[1]=f2bf(va.y); pk.u[2]=f2bf(va.z); pk.u[3]=f2bf(va.w);
    pk.u[4]=f2bf(vb.x); pk.u[5]=f2bf(vb.y); pk.u[6]=f2bf(vb.z); pk.u[7]=f2bf(vb.w);
    *(bf16x8*)(smem + (size_t)(c*XROWS + r)*16) = pk.v;
  }

  f32x4 acc[4][7];
  float cbv[7];
  #pragma unroll
  for (int nf = 0; nf < 7; ++nf) {
    int colg = (nq*7 + nf)*16 + l15;
    cbv[nf] = (colg < Fq) ? cb[colg] : 0.f;
  }
  #pragma unroll
  for (int mf = 0; mf < 4; ++mf)
    #pragma unroll
    for (int nf = 0; nf < 7; ++nf)
      acc[mf][nf] = (f32x4){cbv[nf], cbv[nf], cbv[nf], cbv[nf]};

  __syncthreads();

  for (int step = 0; step < 30; ++step) {
    const int w = step / 10, s = step - w*10;
    const int cbuf = step & 1;
    if (step < 29) {
      const __hip_bfloat16* src = Wp + (size_t)(step+1)*16384;
      unsigned char* dst = smem + (cbuf ? BBUF0 : BBUF1);
      #pragma unroll
      for (int k = 0; k < 4; ++k)
        glds16(src + k*4096 + tid*8, dst + k*8192 + wbase16);
    }
    bf16x8 a[4];
    #pragma unroll
    for (int mf = 0; mf < 4; ++mf) {
      int arow = mh*64 + mf*16 + l15 + w;
      int c = s*4 + l4;
      a[mf] = *(const bf16x8*)(smem + (size_t)(c*XROWS + arow)*16);
    }
    bf16x8 bb[7];
    const unsigned char* bbase = smem + (cbuf ? BBUF1 : BBUF0);
    #pragma unroll
    for (int nf = 0; nf < 7; ++nf) {
      int col = (nq*7 + nf)*16 + l15;
      bb[nf] = *(const bf16x8*)(bbase + (size_t)(l4*512 + col)*16);
    }
    #pragma unroll
    for (int mf = 0; mf < 4; ++mf)
      #pragma unroll
      for (int nf = 0; nf < 7; ++nf)
        acc[mf][nf] = __builtin_amdgcn_mfma_f32_16x16x32_bf16(a[mf], bb[nf], acc[mf][nf], 0, 0, 0);
    __syncthreads();
  }

  #pragma unroll
  for (int k = 0; k < 2; ++k)
    glds16(Ap + k*4096 + tid*8, smem + ABUF0 + k*8192 + wbase16);

  #pragma unroll
  for (int mf = 0; mf < 4; ++mf) {
    #pragma unroll
    for (int nf = 0; nf < 7; ++nf) {
      int colg = (nq*7 + nf)*16 + l15;
      if (colg < 416) {
        #pragma unroll
        for (int i = 0; i < 4; ++i) {
          int row = mh*64 + mf*16 + l4*4 + i;
          float v = fmaxf(acc[mf][nf][i], 0.f);
          *(unsigned short*)(smem + (size_t)((colg >> 3)*128 + row)*16 + (colg & 7)*2) = f2bf(v);
        }
      }
    }
  }
  __syncthreads();

  f32x4 acc2[4][4];
  #pragma unroll
  for (int mf = 0; mf < 4; ++mf)
    #pragma unroll
    for (int nn = 0; nn < 4; ++nn)
      acc2[mf][nn] = (f32x4){0.f,0.f,0.f,0.f};
  const int nf0  = (nq == 0) ? 0 : (1 + 3*nq);
  const int ncnt = (nq == 0) ? 4 : 3;

  for (int s2 = 0; s2 < 13; ++s2) {
    const int cbuf = s2 & 1;
    if (s2 < 12) {
      const __hip_bfloat16* src = Ap + (size_t)(s2+1)*8192;
      unsigned char* dst = smem + (cbuf ? ABUF0 : ABUF1);
      #pragma unroll
      for (int k = 0; k < 2; ++k)
        glds16(src + k*4096 + tid*8, dst + k*8192 + wbase16);
    }
    bf16x8 a2[4];
    #pragma unroll
    for (int mf = 0; mf < 4; ++mf) {
      int row = mh*64 + mf*16 + l15;
      int fchunk = s2*4 + l4;
      a2[mf] = *(const bf16x8*)(smem + (size_t)(fchunk*128 + row)*16);
    }
    bf16x8 b2[4];
    const unsigned char* bbase = smem + (cbuf ? ABUF1 : ABUF0);
    #pragma unroll
    for (int nn = 0; nn < 4; ++nn) {
      if (nn < ncnt) {
        int col = (nf0 + nn)*16 + l15;
        b2[nn] = *(const bf16x8*)(bbase + (size_t)(l4*256 + col)*16);
      }
    }
    #pragma unroll
    for (int mf = 0; mf < 4; ++mf)
      #pragma unroll
      for (int nn = 0; nn < 4; ++nn)
        if (nn < ncnt)
          acc2[mf][nn] = __builtin_amdgcn_mfma_f32_16x16x32_bf16(a2[mf], b2[nn], acc2[mf][nn], 0, 0, 0);
    __syncthreads();
  }

  {
    float abv[4], aqv[4];
    #pragma unroll
    for (int nn = 0; nn < 4; ++nn) {
      int col = (nf0 + nn)*16 + l15;
      bool ok = (nn < ncnt) && (col < Qq);
      abv[nn] = ok ? ab[col] : 0.f;
      aqv[nn] = ok ? aq[col] : 0.f;
    }
    #pragma unroll
    for (int mf = 0; mf < 4; ++mf) {
      #pragma unroll
      for (int i = 0; i < 4; ++i) {
        float p = 0.f;
        #pragma unroll
        for (int nn = 0; nn < 4; ++nn)
          if (nn < ncnt)
            p += tanhf(acc2[mf][nn][i] + abv[nn]) * aqv[nn];
        p += __shfl_xor(p, 1); p += __shfl_xor(p, 2);
        p += __shfl_xor(p, 4); p += __shfl_xor(p, 8);
        if (l15 == 0) atomicAdd(&sscore[mh*64 + mf*16 + l4*4 + i], p);
      }
    }
  }
  __syncthreads();

  if (tid < 4) {
    float mx = -1e30f;
    for (int t = 0; t < Tq; ++t) mx = fmaxf(mx, sscore[tid*32 + t]);
    float sum = 0.f;
    for (int t = 0; t < Tq; ++t) { float e = expf(sscore[tid*32 + t] - mx); sa_[tid*32 + t] = e; sum += e; }
    float inv = 1.f / sum;
    for (int t = 0; t < Tq; ++t) sa_[tid*32 + t] *= inv;
    sa_[tid*32 + 30] = 0.f; sa_[tid*32 + 31] = 0.f;
  }
  __syncthreads();

  {
    const int tt = tid >> 7, fb = tid & 127;
    float rv[4];
    float ls = 0.f, lsq = 0.f;
    #pragma unroll
    for (int q = 0; q < 4; ++q) {
      int f = fb + q*128;
      rv[q] = 0.f;
      if (f < Fq) {
        float r = 0.f;
        const unsigned char* hb = smem + (size_t)(f >> 3)*128*16 + (f & 7)*2;
        for (int t = 0; t < Tq; ++t)
          r += sa_[tt*32 + t] * bf2f(*(const unsigned short*)(hb + (size_t)(tt*32 + t)*16));
        rv[q] = r; ls += r; lsq += r*r;
      }
    }
    #pragma unroll
    for (int off = 32; off >= 1; off >>= 1) { ls += __shfl_xor(ls, off); lsq += __shfl_xor(lsq, off); }
    if (lane == 0) { red_[wid] = ls; red_[8 + wid] = lsq; }
    __syncthreads();
    float tot  = red_[2*tt] + red_[2*tt + 1];
    float totq = red_[8 + 2*tt] + red_[8 + 2*tt + 1];
    float mu = tot * (1.f/Fq);
    float var = totq * (1.f/Fq) - mu*mu;
    float rs = rsqrtf(var + 1e-5f);
    float* dst = (cand ? cand_rep : clicked_rep) + (size_t)(n0 + tt)*Fq;
    #pragma unroll
    for (int q = 0; q < 4; ++q) {
      int f = fb + q*128;
      if (f < Fq) dst[f] = (rv[q] - mu)*rs*lg[f] + lb[f];
    }
  }
}

// ---------------- GI = clicked_rep @ wih^T + bih ----------------
__global__ __launch_bounds__(256) void gi_kernel(
    const float* __restrict__ rep, const float* __restrict__ wih, const float* __restrict__ bih,
    float* __restrict__ gi)
{
  __shared__ __align__(16) float sA[64*80];
  const int tid = threadIdx.x;
  const int rt = blockIdx.x;
  const int g  = blockIdx.y*256 + tid;
  const bool gok = g < G3;
  const float* wr = wih + (size_t)(gok ? g : 0) * Fq;
  float acc[64];
  #pragma unroll
  for (int r = 0; r < 64; ++r) acc[r] = 0.f;
  for (int kt = 0; kt < Fq; kt += 80) {
    __syncthreads();
    for (int i = tid; i < 64*80; i += 256) {
      int r = i / 80, c = i - r*80;
      sA[i] = rep[(size_t)(rt*64 + r)*Fq + kt + c];
    }
    __syncthreads();
    #pragma unroll 2
    for (int k = 0; k < 80; k += 4) {
      float w0 = wr[kt+k], w1 = wr[kt+k+1], w2 = wr[kt+k+2], w3 = wr[kt+k+3];
      #pragma unroll
      for (int r = 0; r < 64; ++r) {
        float4 a4 = *(const float4*)(sA + r*80 + k);
        acc[r] = fmaf(a4.x,w0,fmaf(a4.y,w1,fmaf(a4.z,w2,fmaf(a4.w,w3,acc[r]))));
      }
    }
  }
  if (gok) {
    float bv = bih[g];
    #pragma unroll 1
    for (int r = 0; r < 64; ++r)
      __builtin_nontemporal_store(acc[r] + bv, &gi[(size_t)(rt*64+r)*G3 + g]);
  }
}

// ---------------- GRU: streaming, int8 weights (halved L2 stream) ----------------
__global__ __launch_bounds__(1024) void gru_kernel(
    const float* __restrict__ gi, const signed char* __restrict__ w8,
    const float* __restrict__ wsc, const float* __restrict__ bhh,
    const int* __restrict__ lens, float* __restrict__ user_rep)
{
  __shared__ __align__(16) float shf[Fq];        // fp32 carried h
  __shared__ __align__(16) signed char sh8[Fq];  // int8 copy of h for the matvec
  __shared__ float sgh[G3];
  const int b = blockIdx.x, tid = threadIdx.x;
  const int len = lens[b];
  for (int j = tid; j < Fq; j += 1024) { shf[j] = 0.f; sh8[j] = 0; }
  __syncthreads();
  const int g2 = tid + 1024;
  const bool g2ok = (g2 < G3);                   // tid < 176
  const uint4* w1 = (const uint4*)w8 + tid;      // layout [k16][g][16i8]
  const uint4* w2 = (const uint4*)w8 + (g2ok ? g2 : tid);
  const float sc1 = wsc[tid];
  const float sc2 = g2ok ? wsc[g2] : 0.f;
  const float bb1 = bhh[tid];
  const float bb2 = g2ok ? bhh[g2] : 0.f;
  const float* gb = gi + (size_t)b*Hq*G3;

  for (int t = 0; t < len; ++t) {
    int a1 = 0, a2 = 0;
    const uint4* hp = (const uint4*)sh8;
    #pragma unroll 5
    for (int k16 = 0; k16 < 25; ++k16) {
      uint4 hv = hp[k16];                        // LDS broadcast, 16 int8 of h
      uint4 wv = w1[(size_t)k16*G3];             // coalesced 1KB/wave, L2-resident
      a1 = dot4i8(hv.x, wv.x, a1); a1 = dot4i8(hv.y, wv.y, a1);
      a1 = dot4i8(hv.z, wv.z, a1); a1 = dot4i8(hv.w, wv.w, a1);
      if (g2ok) {
        uint4 vv = w2[(size_t)k16*G3];
        a2 = dot4i8(hv.x, vv.x, a2); a2 = dot4i8(hv.y, vv.y, a2);
        a2 = dot4i8(hv.z, vv.z, a2); a2 = dot4i8(hv.w, vv.w, a2);
      }
    }
    sgh[tid] = (float)a1*sc1 + bb1;
    if (g2ok) sgh[g2] = (float)a2*sc2 + bb2;
    __syncthreads();
    if (tid < Fq) {
      float gr = __builtin_nontemporal_load(&gb[tid]);
      float gz = __builtin_nontemporal_load(&gb[Fq + tid]);
      float gn = __builtin_nontemporal_load(&gb[2*Fq + tid]);
      float r  = sigmoidf_(gr + sgh[tid]);
      float z  = sigmoidf_(gz + sgh[Fq + tid]);
      float nn = tanhf   (gn + r*sgh[2*Fq + tid]);
      float hn = (1.f - z)*nn + z*shf[tid];
      shf[tid] = hn;
      int q = (int)rintf(hn*127.f);              // |h|<=1 provably; clamp for safety
      sh8[tid] = (signed char)max(-127, min(127, q));
    }
    __syncthreads();
    gb += G3;
  }
  for (int j = tid; j < Fq; j += 1024) user_rep[(size_t)b*Fq + j] = shf[j];
}

__global__ __launch_bounds__(64) void score_kernel(
    const float* __restrict__ cand_rep, const float* __restrict__ user_rep,
    float* __restrict__ out)
{
  const int i = blockIdx.x;
  const int b = i / Sq;
  const int lane = threadIdx.x;
  float acc = 0.f;
  for (int f = lane; f < Fq; f += 64) acc = fmaf(cand_rep[(size_t)i*Fq+f], user_rep[(size_t)b*Fq+f], acc);
  #pragma unroll
  for (int off = 32; off >= 1; off >>= 1) acc += __shfl_xor(acc, off);
  if (lane == 0) out[i] = acc;
}

extern "C" void kernel_launch(void* const* d_in, const int* in_sizes, int n_in,
                              void* d_out, int out_size, void* d_ws, size_t ws_size,
                              hipStream_t stream)
{
  const float* cand_emb = (const float*)d_in[0];
  const float* clk_emb  = (const float*)d_in[1];
  const int*   lens     = (const int*)  d_in[2];
  const float* c_cw = (const float*)d_in[3];
  const float* c_cb = (const float*)d_in[4];
  const float* c_aW = (const float*)d_in[5];
  const float* c_ab = (const float*)d_in[6];
  const float* c_aq = (const float*)d_in[7];
  const float* c_lg = (const float*)d_in[8];
  const float* c_lb = (const float*)d_in[9];
  const float* u_cw = (const float*)d_in[10];
  const float* u_cb = (const float*)d_in[11];
  const float* u_aW = (const float*)d_in[12];
  const float* u_ab = (const float*)d_in[13];
  const float* u_aq = (const float*)d_in[14];
  const float* u_lg = (const float*)d_in[15];
  const float* u_lb = (const float*)d_in[16];
  const float* wih  = (const float*)d_in[17];
  const float* whh  = (const float*)d_in[18];
  const float* bih  = (const float*)d_in[19];
  const float* bhh  = (const float*)d_in[20];

  float* ws = (float*)d_ws;
  float* cand_rep    = ws;                        // 128,000 f
  float* clicked_rep = cand_rep + NCAND*Fq;       // +1,280,000
  float* gi          = clicked_rep + NCLK*Fq;     // +3,840,000
  float* user_rep    = gi + (size_t)NCLK*G3;      // +25,600
  signed char* w8    = (signed char*)(user_rep + Bq*Fq);  // 480,000 B (16B-aligned)
  float* wsc         = (float*)(w8 + 480000);             // 1200 f
  // bf16 encoder-prep buffers overlay gi (dead until gi_kernel runs)
  __hip_bfloat16* convprep = (__hip_bfloat16*)gi;
  __hip_bfloat16* attprep  = (__hip_bfloat16*)(gi + 491520);

  conv_prep_kernel<<<(2*30*16384 + 255)/256, 256, 0, stream>>>(c_cw, u_cw, convprep);
  att_prep_kernel<<<(2*13*8192 + 255)/256, 256, 0, stream>>>(c_aW, u_aW, attprep);
  whh_i8_prep_kernel<<<G3, 64, 0, stream>>>(whh, w8, wsc);

  encode_mfma_kernel<<<(NCAND + NCLK)/4, 512, 0, stream>>>(
      cand_emb, clk_emb, convprep, attprep,
      c_cb, c_ab, c_aq, c_lg, c_lb,
      u_cb, u_ab, u_aq, u_lg, u_lb,
      cand_rep, clicked_rep);

  gi_kernel<<<dim3(NCLK/64, 5), 256, 0, stream>>>(clicked_rep, wih, bih, gi);

  gru_kernel<<<Bq, 1024, 0, stream>>>(gi, w8, wsc, bhh, lens, user_rep);

  score_kernel<<<NCAND, 64, 0, stream>>>(cand_rep, user_rep, (float*)d_out);
}

// Round 11
// 501.138 us; speedup vs baseline: 3.8982x; 1.3960x over previous
//
#include <hip/hip_runtime.h>
#include <hip/hip_bf16.h>
#include <math.h>

#define Bq 64
#define Sq 5
#define Hq 50
#define Tq 30
#define Dq 300
#define Fq 400
#define Qq 200
#define G3 1200
#define NCAND (Bq*Sq)
#define NCLK  (Bq*Hq)

typedef __attribute__((ext_vector_type(8))) short bf16x8;
typedef __attribute__((ext_vector_type(8))) _Float16 f16x8;
typedef __attribute__((ext_vector_type(4))) float f32x4;

__device__ __forceinline__ float sigmoidf_(float x){ return 1.f/(1.f+expf(-x)); }
__device__ __forceinline__ unsigned short f2bf(float x){
  __hip_bfloat16 b = __float2bfloat16(x);
  return *reinterpret_cast<unsigned short*>(&b);
}
__device__ __forceinline__ float bf2f(unsigned short u){
  __hip_bfloat16 b; *reinterpret_cast<unsigned short*>(&b) = u;
  return __bfloat162float(b);
}
// async global->LDS DMA, 16B per lane (wave-uniform LDS base, HW adds lane*16)
typedef __attribute__((address_space(1))) const unsigned g_u32;
typedef __attribute__((address_space(3))) unsigned l_u32;
__device__ __forceinline__ void glds16(const void* g, void* l){
  __builtin_amdgcn_global_load_lds((g_u32*)g, (l_u32*)l, 16, 0, 0);
}
// int8x4 dot with i32 accumulate
__device__ __forceinline__ int dot4i8(unsigned a, unsigned b, int c){
#if defined(__has_builtin) && __has_builtin(__builtin_amdgcn_sdot4)
  return __builtin_amdgcn_sdot4((int)a, (int)b, c, false);
#else
  int r = c;
  r += (int)(signed char)(a)      * (int)(signed char)(b);
  r += (int)(signed char)(a>>8)   * (int)(signed char)(b>>8);
  r += (int)(signed char)(a>>16)  * (int)(signed char)(b>>16);
  r += (int)(signed char)(a>>24)  * (int)(signed char)(b>>24);
  return r;
#endif
}

// ---------------- weight prep (one-time per call, tiny) ----------------
__global__ __launch_bounds__(256) void conv_prep_kernel(
    const float* __restrict__ c_cw, const float* __restrict__ u_cw,
    __hip_bfloat16* __restrict__ out)
{
  const int PER = 30*16384;
  int idx = blockIdx.x*256 + threadIdx.x;
  if (idx >= 2*PER) return;
  int enc = idx / PER, rem = idx - enc*PER;
  int chunk = rem >> 14;
  int e = rem & 16383;
  int sub = e >> 12;
  int col = (e >> 3) & 511;
  int j = e & 7;
  int w = chunk / 10, s = chunk - w*10;
  int d = s*32 + sub*8 + j;
  const float* cw = enc ? u_cw : c_cw;
  float v = (d < Dq && col < Fq) ? cw[(w*Dq + d)*Fq + col] : 0.f;
  out[idx] = __float2bfloat16(v);
}

__global__ __launch_bounds__(256) void att_prep_kernel(
    const float* __restrict__ c_aW, const float* __restrict__ u_aW,
    __hip_bfloat16* __restrict__ out)
{
  const int PER = 13*8192;
  int idx = blockIdx.x*256 + threadIdx.x;
  if (idx >= 2*PER) return;
  int enc = idx / PER, rem = idx - enc*PER;
  int chunk = rem >> 13;
  int e = rem & 8191;
  int sub = e >> 11;
  int col = (e >> 3) & 255;
  int j = e & 7;
  int k = chunk*32 + sub*8 + j;
  const float* aW = enc ? u_aW : c_aW;
  float v = (k < Fq && col < Qq) ? aW[k*Qq + col] : 0.f;
  out[idx] = __float2bfloat16(v);
}

// whh [1200,400] f32 -> int8 with per-row scale. Layout [k16 25][g 1200][16].
__global__ __launch_bounds__(64) void whh_i8_prep_kernel(
    const float* __restrict__ whh, signed char* __restrict__ w8, float* __restrict__ wsc)
{
  const int g = blockIdx.x;
  const int lane = threadIdx.x;
  const float* row = whh + (size_t)g*Fq;
  float mx = 0.f;
  for (int k = lane; k < Fq; k += 64) mx = fmaxf(mx, fabsf(row[k]));
  #pragma unroll
  for (int off = 32; off >= 1; off >>= 1) mx = fmaxf(mx, __shfl_xor(mx, off));
  float inv = (mx > 0.f) ? 127.f/mx : 0.f;
  if (lane == 0) wsc[g] = mx * (1.f/16129.f);
  for (int k = lane; k < Fq; k += 64) {
    int q = (int)rintf(row[k]*inv);
    q = max(-127, min(127, q));
    w8[((size_t)(k >> 4)*G3 + g)*16 + (k & 15)] = (signed char)q;
  }
}

// wih [1200,400] f32 -> f16 MFMA-B chunks [13 s][4 sub][1200 g][8 j], k=s*32+sub*8+j
__global__ __launch_bounds__(256) void wihT_prep_kernel(
    const float* __restrict__ wih, _Float16* __restrict__ out)
{
  const int TOT = 13*4*G3*8;   // 499,200
  int idx = blockIdx.x*256 + threadIdx.x;
  if (idx >= TOT) return;
  int j = idx & 7;
  int g = (idx >> 3) % G3;
  int q = (idx >> 3) / G3;
  int sub = q & 3, s = q >> 2;
  int k = s*32 + sub*8 + j;
  out[idx] = (k < Fq) ? (_Float16)wih[(size_t)g*Fq + k] : (_Float16)0.f;
}

// ---------------- fused encoder (round 9: MFMA + global_load_lds staging) ----------
#define XROWS 137
#define XBYTES (40*XROWS*16)
#define BBUF0 XBYTES
#define BCHUNK 32768
#define BBUF1 (BBUF0 + BCHUNK)
#define ABUF0 (52*128*16)
#define ACHUNK 16384
#define ABUF1 (ABUF0 + ACHUNK)
#define SCRATCH (BBUF1 + BCHUNK)
#define SMEM_BYTES (SCRATCH + 1088)

__global__ __launch_bounds__(512, 2) void encode_mfma_kernel(
    const float* __restrict__ cand_emb, const float* __restrict__ clk_emb,
    const __hip_bfloat16* __restrict__ convprep,
    const __hip_bfloat16* __restrict__ attprep,
    const float* __restrict__ c_cb, const float* __restrict__ c_ab, const float* __restrict__ c_aq,
    const float* __restrict__ c_lg, const float* __restrict__ c_lb,
    const float* __restrict__ u_cb, const float* __restrict__ u_ab, const float* __restrict__ u_aq,
    const float* __restrict__ u_lg, const float* __restrict__ u_lb,
    float* __restrict__ cand_rep, float* __restrict__ clicked_rep)
{
  __shared__ __align__(16) unsigned char smem[SMEM_BYTES];
  float* sscore = (float*)(smem + SCRATCH);
  float* sa_    = sscore + 128;
  float* red_   = sa_ + 128;

  const int b = blockIdx.x, tid = threadIdx.x;
  const bool cand = b < (NCAND/4);
  const int n0 = cand ? b*4 : (b - NCAND/4)*4;
  const float* x = (cand ? cand_emb : clk_emb) + (size_t)n0*Tq*Dq;
  const __hip_bfloat16* Wp = convprep + (cand ? 0 : 30*16384);
  const __hip_bfloat16* Ap = attprep  + (cand ? 0 : 13*8192);
  const float* cb = cand ? c_cb : u_cb;
  const float* ab = cand ? c_ab : u_ab;
  const float* aq = cand ? c_aq : u_aq;
  const float* lg = cand ? c_lg : u_lg;
  const float* lb = cand ? c_lb : u_lb;

  const int lane = tid & 63, wid = tid >> 6;
  const int mh = wid >> 2, nq = wid & 3;
  const int l15 = lane & 15, l4 = lane >> 4;
  const int wbase16 = (tid & ~63)*16;

  if (tid < 128) sscore[tid] = 0.f;

  #pragma unroll
  for (int k = 0; k < 4; ++k)
    glds16(Wp + k*4096 + tid*8, smem + BBUF0 + k*8192 + wbase16);

  for (int i = tid; i < 40*XROWS; i += 512) {
    int c = i % 40, r = i / 40;
    f32x4 va = (f32x4){0.f,0.f,0.f,0.f}, vb = (f32x4){0.f,0.f,0.f,0.f};
    if (r < 128) {
      int lr = r & 31, tt = r >> 5;
      if (lr >= 1 && lr <= 30) {
        int t = lr - 1, d0 = c*8;
        if (d0 < Dq) {
          const f32x4* src = (const f32x4*)(x + (size_t)tt*Tq*Dq + t*Dq + d0);
          va = __builtin_nontemporal_load(src);
          if (d0 + 4 < Dq) vb = __builtin_nontemporal_load(src + 1);
        }
      }
    }
    union { bf16x8 v; unsigned short u[8]; } pk;
    pk.u[0]=f2bf(va.x); pk.u[1]=f2bf(va.y); pk.u[2]=f2bf(va.z); pk.u[3]=f2bf(va.w);
    pk.u[4]=f2bf(vb.x); pk.u[5]=f2bf(vb.y); pk.u[6]=f2bf(vb.z); pk.u[7]=f2bf(vb.w);
    *(bf16x8*)(smem + (size_t)(c*XROWS + r)*16) = pk.v;
  }

  f32x4 acc[4][7];
  float cbv[7];
  #pragma unroll
  for (int nf = 0; nf < 7; ++nf) {
    int colg = (nq*7 + nf)*16 + l15;
    cbv[nf] = (colg < Fq) ? cb[colg] : 0.f;
  }
  #pragma unroll
  for (int mf = 0; mf < 4; ++mf)
    #pragma unroll
    for (int nf = 0; nf < 7; ++nf)
      acc[mf][nf] = (f32x4){cbv[nf], cbv[nf], cbv[nf], cbv[nf]};

  __syncthreads();

  for (int step = 0; step < 30; ++step) {
    const int w = step / 10, s = step - w*10;
    const int cbuf = step & 1;
    if (step < 29) {
      const __hip_bfloat16* src = Wp + (size_t)(step+1)*16384;
      unsigned char* dst = smem + (cbuf ? BBUF0 : BBUF1);
      #pragma unroll
      for (int k = 0; k < 4; ++k)
        glds16(src + k*4096 + tid*8, dst + k*8192 + wbase16);
    }
    bf16x8 a[4];
    #pragma unroll
    for (int mf = 0; mf < 4; ++mf) {
      int arow = mh*64 + mf*16 + l15 + w;
      int c = s*4 + l4;
      a[mf] = *(const bf16x8*)(smem + (size_t)(c*XROWS + arow)*16);
    }
    bf16x8 bb[7];
    const unsigned char* bbase = smem + (cbuf ? BBUF1 : BBUF0);
    #pragma unroll
    for (int nf = 0; nf < 7; ++nf) {
      int col = (nq*7 + nf)*16 + l15;
      bb[nf] = *(const bf16x8*)(bbase + (size_t)(l4*512 + col)*16);
    }
    #pragma unroll
    for (int mf = 0; mf < 4; ++mf)
      #pragma unroll
      for (int nf = 0; nf < 7; ++nf)
        acc[mf][nf] = __builtin_amdgcn_mfma_f32_16x16x32_bf16(a[mf], bb[nf], acc[mf][nf], 0, 0, 0);
    __syncthreads();
  }

  #pragma unroll
  for (int k = 0; k < 2; ++k)
    glds16(Ap + k*4096 + tid*8, smem + ABUF0 + k*8192 + wbase16);

  #pragma unroll
  for (int mf = 0; mf < 4; ++mf) {
    #pragma unroll
    for (int nf = 0; nf < 7; ++nf) {
      int colg = (nq*7 + nf)*16 + l15;
      if (colg < 416) {
        #pragma unroll
        for (int i = 0; i < 4; ++i) {
          int row = mh*64 + mf*16 + l4*4 + i;
          float v = fmaxf(acc[mf][nf][i], 0.f);
          *(unsigned short*)(smem + (size_t)((colg >> 3)*128 + row)*16 + (colg & 7)*2) = f2bf(v);
        }
      }
    }
  }
  __syncthreads();

  f32x4 acc2[4][4];
  #pragma unroll
  for (int mf = 0; mf < 4; ++mf)
    #pragma unroll
    for (int nn = 0; nn < 4; ++nn)
      acc2[mf][nn] = (f32x4){0.f,0.f,0.f,0.f};
  const int nf0  = (nq == 0) ? 0 : (1 + 3*nq);
  const int ncnt = (nq == 0) ? 4 : 3;

  for (int s2 = 0; s2 < 13; ++s2) {
    const int cbuf = s2 & 1;
    if (s2 < 12) {
      const __hip_bfloat16* src = Ap + (size_t)(s2+1)*8192;
      unsigned char* dst = smem + (cbuf ? ABUF0 : ABUF1);
      #pragma unroll
      for (int k = 0; k < 2; ++k)
        glds16(src + k*4096 + tid*8, dst + k*8192 + wbase16);
    }
    bf16x8 a2[4];
    #pragma unroll
    for (int mf = 0; mf < 4; ++mf) {
      int row = mh*64 + mf*16 + l15;
      int fchunk = s2*4 + l4;
      a2[mf] = *(const bf16x8*)(smem + (size_t)(fchunk*128 + row)*16);
    }
    bf16x8 b2[4];
    const unsigned char* bbase = smem + (cbuf ? ABUF1 : ABUF0);
    #pragma unroll
    for (int nn = 0; nn < 4; ++nn) {
      if (nn < ncnt) {
        int col = (nf0 + nn)*16 + l15;
        b2[nn] = *(const bf16x8*)(bbase + (size_t)(l4*256 + col)*16);
      }
    }
    #pragma unroll
    for (int mf = 0; mf < 4; ++mf)
      #pragma unroll
      for (int nn = 0; nn < 4; ++nn)
        if (nn < ncnt)
          acc2[mf][nn] = __builtin_amdgcn_mfma_f32_16x16x32_bf16(a2[mf], b2[nn], acc2[mf][nn], 0, 0, 0);
    __syncthreads();
  }

  {
    float abv[4], aqv[4];
    #pragma unroll
    for (int nn = 0; nn < 4; ++nn) {
      int col = (nf0 + nn)*16 + l15;
      bool ok = (nn < ncnt) && (col < Qq);
      abv[nn] = ok ? ab[col] : 0.f;
      aqv[nn] = ok ? aq[col] : 0.f;
    }
    #pragma unroll
    for (int mf = 0; mf < 4; ++mf) {
      #pragma unroll
      for (int i = 0; i < 4; ++i) {
        float p = 0.f;
        #pragma unroll
        for (int nn = 0; nn < 4; ++nn)
          if (nn < ncnt)
            p += tanhf(acc2[mf][nn][i] + abv[nn]) * aqv[nn];
        p += __shfl_xor(p, 1); p += __shfl_xor(p, 2);
        p += __shfl_xor(p, 4); p += __shfl_xor(p, 8);
        if (l15 == 0) atomicAdd(&sscore[mh*64 + mf*16 + l4*4 + i], p);
      }
    }
  }
  __syncthreads();

  if (tid < 4) {
    float mx = -1e30f;
    for (int t = 0; t < Tq; ++t) mx = fmaxf(mx, sscore[tid*32 + t]);
    float sum = 0.f;
    for (int t = 0; t < Tq; ++t) { float e = expf(sscore[tid*32 + t] - mx); sa_[tid*32 + t] = e; sum += e; }
    float inv = 1.f / sum;
    for (int t = 0; t < Tq; ++t) sa_[tid*32 + t] *= inv;
    sa_[tid*32 + 30] = 0.f; sa_[tid*32 + 31] = 0.f;
  }
  __syncthreads();

  {
    const int tt = tid >> 7, fb = tid & 127;
    float rv[4];
    float ls = 0.f, lsq = 0.f;
    #pragma unroll
    for (int q = 0; q < 4; ++q) {
      int f = fb + q*128;
      rv[q] = 0.f;
      if (f < Fq) {
        float r = 0.f;
        const unsigned char* hb = smem + (size_t)(f >> 3)*128*16 + (f & 7)*2;
        for (int t = 0; t < Tq; ++t)
          r += sa_[tt*32 + t] * bf2f(*(const unsigned short*)(hb + (size_t)(tt*32 + t)*16));
        rv[q] = r; ls += r; lsq += r*r;
      }
    }
    #pragma unroll
    for (int off = 32; off >= 1; off >>= 1) { ls += __shfl_xor(ls, off); lsq += __shfl_xor(lsq, off); }
    if (lane == 0) { red_[wid] = ls; red_[8 + wid] = lsq; }
    __syncthreads();
    float tot  = red_[2*tt] + red_[2*tt + 1];
    float totq = red_[8 + 2*tt] + red_[8 + 2*tt + 1];
    float mu = tot * (1.f/Fq);
    float var = totq * (1.f/Fq) - mu*mu;
    float rs = rsqrtf(var + 1e-5f);
    float* dst = (cand ? cand_rep : clicked_rep) + (size_t)(n0 + tt)*Fq;
    #pragma unroll
    for (int q = 0; q < 4; ++q) {
      int f = fb + q*128;
      if (f < Fq) dst[f] = (rv[q] - mu)*rs*lg[f] + lb[f];
    }
  }
}

// ---------------- GI = clicked_rep @ wih^T + bih  (f16 MFMA GEMM) ----------------
// M=3200 (BM=64), N=1200 (BN=240), K=416 padded (13 steps of 32).
// grid (50, 5), 256 threads (4 waves; wave wv owns rows wv*16..+16, all 240 cols).
__global__ __launch_bounds__(256) void gi_mfma_kernel(
    const float* __restrict__ rep, const _Float16* __restrict__ wihT,
    const float* __restrict__ bih, float* __restrict__ gi)
{
  __shared__ __align__(16) _Float16 As[2][4][64][8];    // 2 x 4KB
  __shared__ __align__(16) _Float16 Bs[2][4][240][8];   // 2 x 15KB
  const int tid = threadIdx.x;
  const int bm = blockIdx.x;     // 0..49
  const int nc = blockIdx.y;     // 0..4
  const int lane = tid & 63, wv = tid >> 6;
  const int l15 = lane & 15, l4 = lane >> 4;
  const int arow = tid >> 2, asub = tid & 3;   // A staging task (256 = 64x4)

  f32x4 acc[15];
  #pragma unroll
  for (int nf = 0; nf < 15; ++nf) acc[nf] = (f32x4){0.f,0.f,0.f,0.f};

  // stage step s into parity p
  auto stage = [&](int p, int s){
    // A: rep row fp32 -> f16 [sub][row][8]
    {
      f32x4 v0 = (f32x4){0.f,0.f,0.f,0.f}, v1 = v0;
      int k0 = s*32 + asub*8;
      if (k0 < Fq) {
        const f32x4* src = (const f32x4*)(rep + (size_t)(bm*64 + arow)*Fq + k0);
        v0 = src[0]; v1 = src[1];
      }
      union { f16x8 v; _Float16 e[8]; } pk;
      pk.e[0]=(_Float16)v0.x; pk.e[1]=(_Float16)v0.y; pk.e[2]=(_Float16)v0.z; pk.e[3]=(_Float16)v0.w;
      pk.e[4]=(_Float16)v1.x; pk.e[5]=(_Float16)v1.y; pk.e[6]=(_Float16)v1.z; pk.e[7]=(_Float16)v1.w;
      *(f16x8*)&As[p][asub][arow][0] = pk.v;
    }
    // B: pre-chunked f16, straight uint4 copy
    const _Float16* bsrc = wihT + (size_t)s*4*G3*8;
    uint4* bdst = (uint4*)&Bs[p][0][0][0];
    for (int i = tid; i < 960; i += 256) {
      int sub = i / 240, col = i - sub*240;
      bdst[i] = *(const uint4*)(bsrc + ((size_t)sub*G3 + nc*240 + col)*8);
    }
  };

  stage(0, 0);
  __syncthreads();

  for (int s = 0; s < 13; ++s) {
    const int p = s & 1;
    if (s < 12) stage(p ^ 1, s + 1);
    f16x8 a = *(const f16x8*)&As[p][l4][wv*16 + l15][0];
    #pragma unroll
    for (int nf = 0; nf < 15; ++nf) {
      f16x8 bfr = *(const f16x8*)&Bs[p][l4][nf*16 + l15][0];
      acc[nf] = __builtin_amdgcn_mfma_f32_16x16x32_f16(a, bfr, acc[nf], 0, 0, 0);
    }
    __syncthreads();
  }

  #pragma unroll
  for (int nf = 0; nf < 15; ++nf) {
    int g = nc*240 + nf*16 + l15;
    float bv = bih[g];
    #pragma unroll
    for (int i = 0; i < 4; ++i) {
      int row = bm*64 + wv*16 + l4*4 + i;
      gi[(size_t)row*G3 + g] = acc[nf][i] + bv;
    }
  }
}

// ---------------- GRU: streaming, int8 weights (proven 284 us) ----------------
__global__ __launch_bounds__(1024) void gru_kernel(
    const float* __restrict__ gi, const signed char* __restrict__ w8,
    const float* __restrict__ wsc, const float* __restrict__ bhh,
    const int* __restrict__ lens, float* __restrict__ user_rep)
{
  __shared__ __align__(16) float shf[Fq];
  __shared__ __align__(16) signed char sh8[Fq];
  __shared__ float sgh[G3];
  const int b = blockIdx.x, tid = threadIdx.x;
  const int len = lens[b];
  for (int j = tid; j < Fq; j += 1024) { shf[j] = 0.f; sh8[j] = 0; }
  __syncthreads();
  const int g2 = tid + 1024;
  const bool g2ok = (g2 < G3);
  const uint4* w1 = (const uint4*)w8 + tid;
  const uint4* w2 = (const uint4*)w8 + (g2ok ? g2 : tid);
  const float sc1 = wsc[tid];
  const float sc2 = g2ok ? wsc[g2] : 0.f;
  const float bb1 = bhh[tid];
  const float bb2 = g2ok ? bhh[g2] : 0.f;
  const float* gb = gi + (size_t)b*Hq*G3;

  for (int t = 0; t < len; ++t) {
    int a1 = 0, a2 = 0;
    const uint4* hp = (const uint4*)sh8;
    #pragma unroll 5
    for (int k16 = 0; k16 < 25; ++k16) {
      uint4 hv = hp[k16];
      uint4 wv = w1[(size_t)k16*G3];
      a1 = dot4i8(hv.x, wv.x, a1); a1 = dot4i8(hv.y, wv.y, a1);
      a1 = dot4i8(hv.z, wv.z, a1); a1 = dot4i8(hv.w, wv.w, a1);
      if (g2ok) {
        uint4 vv = w2[(size_t)k16*G3];
        a2 = dot4i8(hv.x, vv.x, a2); a2 = dot4i8(hv.y, vv.y, a2);
        a2 = dot4i8(hv.z, vv.z, a2); a2 = dot4i8(hv.w, vv.w, a2);
      }
    }
    sgh[tid] = (float)a1*sc1 + bb1;
    if (g2ok) sgh[g2] = (float)a2*sc2 + bb2;
    __syncthreads();
    if (tid < Fq) {
      float gr = __builtin_nontemporal_load(&gb[tid]);
      float gz = __builtin_nontemporal_load(&gb[Fq + tid]);
      float gn = __builtin_nontemporal_load(&gb[2*Fq + tid]);
      float r  = sigmoidf_(gr + sgh[tid]);
      float z  = sigmoidf_(gz + sgh[Fq + tid]);
      float nn = tanhf   (gn + r*sgh[2*Fq + tid]);
      float hn = (1.f - z)*nn + z*shf[tid];
      shf[tid] = hn;
      int q = (int)rintf(hn*127.f);
      sh8[tid] = (signed char)max(-127, min(127, q));
    }
    __syncthreads();
    gb += G3;
  }
  for (int j = tid; j < Fq; j += 1024) user_rep[(size_t)b*Fq + j] = shf[j];
}

__global__ __launch_bounds__(64) void score_kernel(
    const float* __restrict__ cand_rep, const float* __restrict__ user_rep,
    float* __restrict__ out)
{
  const int i = blockIdx.x;
  const int b = i / Sq;
  const int lane = threadIdx.x;
  float acc = 0.f;
  for (int f = lane; f < Fq; f += 64) acc = fmaf(cand_rep[(size_t)i*Fq+f], user_rep[(size_t)b*Fq+f], acc);
  #pragma unroll
  for (int off = 32; off >= 1; off >>= 1) acc += __shfl_xor(acc, off);
  if (lane == 0) out[i] = acc;
}

extern "C" void kernel_launch(void* const* d_in, const int* in_sizes, int n_in,
                              void* d_out, int out_size, void* d_ws, size_t ws_size,
                              hipStream_t stream)
{
  const float* cand_emb = (const float*)d_in[0];
  const float* clk_emb  = (const float*)d_in[1];
  const int*   lens     = (const int*)  d_in[2];
  const float* c_cw = (const float*)d_in[3];
  const float* c_cb = (const float*)d_in[4];
  const float* c_aW = (const float*)d_in[5];
  const float* c_ab = (const float*)d_in[6];
  const float* c_aq = (const float*)d_in[7];
  const float* c_lg = (const float*)d_in[8];
  const float* c_lb = (const float*)d_in[9];
  const float* u_cw = (const float*)d_in[10];
  const float* u_cb = (const float*)d_in[11];
  const float* u_aW = (const float*)d_in[12];
  const float* u_ab = (const float*)d_in[13];
  const float* u_aq = (const float*)d_in[14];
  const float* u_lg = (const float*)d_in[15];
  const float* u_lb = (const float*)d_in[16];
  const float* wih  = (const float*)d_in[17];
  const float* whh  = (const float*)d_in[18];
  const float* bih  = (const float*)d_in[19];
  const float* bhh  = (const float*)d_in[20];

  float* ws = (float*)d_ws;
  float* cand_rep    = ws;                        // 128,000 f
  float* clicked_rep = cand_rep + NCAND*Fq;       // +1,280,000
  float* gi          = clicked_rep + NCLK*Fq;     // +3,840,000
  float* user_rep    = gi + (size_t)NCLK*G3;      // +25,600
  signed char* w8    = (signed char*)(user_rep + Bq*Fq);  // 480,000 B
  float* wsc         = (float*)(w8 + 480000);             // 1,200 f
  _Float16* wihT16   = (_Float16*)(wsc + 1200);           // 499,200 halves
  // bf16 encoder-prep buffers overlay gi (dead until gi_mfma overwrites gi later)
  __hip_bfloat16* convprep = (__hip_bfloat16*)gi;
  __hip_bfloat16* attprep  = (__hip_bfloat16*)(gi + 491520);

  conv_prep_kernel<<<(2*30*16384 + 255)/256, 256, 0, stream>>>(c_cw, u_cw, convprep);
  att_prep_kernel<<<(2*13*8192 + 255)/256, 256, 0, stream>>>(c_aW, u_aW, attprep);
  whh_i8_prep_kernel<<<G3, 64, 0, stream>>>(whh, w8, wsc);
  wihT_prep_kernel<<<(13*4*G3*8 + 255)/256, 256, 0, stream>>>(wih, wihT16);

  encode_mfma_kernel<<<(NCAND + NCLK)/4, 512, 0, stream>>>(
      cand_emb, clk_emb, convprep, attprep,
      c_cb, c_ab, c_aq, c_lg, c_lb,
      u_cb, u_ab, u_aq, u_lg, u_lb,
      cand_rep, clicked_rep);

  gi_mfma_kernel<<<dim3(NCLK/64, 5), 256, 0, stream>>>(clicked_rep, wihT16, bih, gi);

  gru_kernel<<<Bq, 1024, 0, stream>>>(gi, w8, wsc, bhh, lens, user_rep);

  score_kernel<<<NCAND, 64, 0, stream>>>(cand_rep, user_rep, (float*)d_out);
}